// Round 11
// baseline (272.595 us; speedup 1.0000x reference)
//
#include <hip/hip_runtime.h>

#define B_ 2
#define T_ 2048
#define C_ 2048
#define NH_ 16
#define NKV_ 4
#define HD_ 128
#define M_ 4096          // B*T
#define NQKV_ 3072

typedef __bf16 bf16x8 __attribute__((ext_vector_type(8)));
typedef float f32x4 __attribute__((ext_vector_type(4)));
typedef float f32x16 __attribute__((ext_vector_type(16)));

__device__ __forceinline__ unsigned short f2bf(float f) {
  union { float f; unsigned u; } c{f};
  unsigned u = c.u + 0x7FFFu + ((c.u >> 16) & 1u);
  return (unsigned short)(u >> 16);
}

#define GLOAD_LDS16(g, l)                                        \
  __builtin_amdgcn_global_load_lds(                              \
      (const __attribute__((address_space(1))) void*)(g),        \
      (__attribute__((address_space(3))) void*)(l), 16, 0, 0)

// ---------------- RoPE cos/sin table: rt[t*64+i] = {cos,sin}(t * 10000^(-2i/128))
__global__ void rope_table_kernel(float2* __restrict__ rt) {
  int t = blockIdx.x, i = threadIdx.x;  // 2048 x 64
  float inv = powf(10000.f, -(float)(2 * i) / 128.f);
  float s, c;
  sincosf((float)t * inv, &s, &c);
  rt[t * 64 + i] = make_float2(c, s);
}

// ---------------- x f32 -> bf16 (vectorized)
__global__ void convx_kernel(const float* __restrict__ x, unsigned short* __restrict__ xb, int n4) {
  int i = blockIdx.x * blockDim.x + threadIdx.x;
  if (i >= n4) return;
  float4 v = reinterpret_cast<const float4*>(x)[i];
  union { ushort4 u; unsigned short s[4]; } o;
  o.s[0] = f2bf(v.x); o.s[1] = f2bf(v.y); o.s[2] = f2bf(v.z); o.s[3] = f2bf(v.w);
  reinterpret_cast<ushort4*>(xb)[i] = o.u;
}

// ---------------- all 4 weights (K x N, f32) -> Wt (N x K, bf16), one launch
__global__ void transpose_conv4_kernel(const float* __restrict__ Wq, const float* __restrict__ Wk,
                                       const float* __restrict__ Wv, const float* __restrict__ Wp,
                                       unsigned short* __restrict__ wt) {
  __shared__ float tile[32][33];
  int id = blockIdx.x;
  const float* W;
  unsigned short* Wt;
  int N, bx, by;
  if (id < 4096)      { W = Wq; Wt = wt;                          N = 2048; int u = id;        bx = u & 63; by = u >> 6; }
  else if (id < 5120) { W = Wk; Wt = wt + (size_t)2048 * 2048;    N = 512;  int u = id - 4096; bx = u & 15; by = u >> 4; }
  else if (id < 6144) { W = Wv; Wt = wt + (size_t)2560 * 2048;    N = 512;  int u = id - 5120; bx = u & 15; by = u >> 4; }
  else                { W = Wp; Wt = wt + (size_t)3072 * 2048;    N = 2048; int u = id - 6144; bx = u & 63; by = u >> 6; }
  const int K = 2048;
  bx *= 32; by *= 32;
  int tx = threadIdx.x & 31, ty = threadIdx.x >> 5;  // 32x8
#pragma unroll
  for (int r = 0; r < 32; r += 8)
    tile[ty + r][tx] = W[(size_t)(by + ty + r) * N + bx + tx];
  __syncthreads();
#pragma unroll
  for (int r = 0; r < 32; r += 8)
    Wt[(size_t)(bx + ty + r) * K + by + tx] = f2bf(tile[tx][ty + r]);
}

// ---------------- bf16 GEMM: 128x128 tile, BK=32; wave = 32-row x 128-col strip.
// MODE 0: plain f32 output (proj). MODE 1: fused QKV epilogue — q (rope) -> qb,
// k (rope) -> kt2 fragment order, v -> vt2 fragment order.
template <int MODE>
__global__ __launch_bounds__(256) void gemm_bf16(const unsigned short* __restrict__ A,
                                                 const unsigned short* __restrict__ Bt,
                                                 float* __restrict__ Cout,
                                                 unsigned short* __restrict__ qb,
                                                 unsigned short* __restrict__ kt2,
                                                 unsigned short* __restrict__ vt2,
                                                 const float2* __restrict__ rt,
                                                 int M, int N, int K) {
  constexpr int BK = 32;
  __shared__ __align__(16) unsigned short Al[2][128 * BK];
  __shared__ __align__(16) unsigned short Bl[2][128 * BK];
  int tid = threadIdx.x, w = tid >> 6, lane = tid & 63;
  int l15 = lane & 15, l4 = lane >> 4;
  size_t arow0 = (size_t)blockIdx.y * 128;
  size_t brow0 = (size_t)blockIdx.x * 128;

  f32x4 acc[2][8];
#pragma unroll
  for (int mi = 0; mi < 2; ++mi)
#pragma unroll
    for (int ni = 0; ni < 8; ++ni) acc[mi][ni] = (f32x4){0.f, 0.f, 0.f, 0.f};

  auto stage = [&](int buf, int k0) {
#pragma unroll
    for (int i = 0; i < 2; ++i) {
      int c = i * 256 + w * 64 + lane;
      const unsigned short* g = A + (arow0 + (c >> 2)) * K + k0 + (c & 3) * 8;
      GLOAD_LDS16(g, &Al[buf][(i * 4 + w) * 512]);
    }
#pragma unroll
    for (int i = 0; i < 2; ++i) {
      int c = i * 256 + w * 64 + lane;
      const unsigned short* g = Bt + (brow0 + (c >> 2)) * K + k0 + (c & 3) * 8;
      GLOAD_LDS16(g, &Bl[buf][(i * 4 + w) * 512]);
    }
  };

  stage(0, 0);
  __syncthreads();
  int NT = K / BK, cur = 0;
  for (int kt = 0; kt < NT; ++kt) {
    if (kt + 1 < NT) stage(cur ^ 1, (kt + 1) * BK);
    const unsigned short* Ab = &Al[cur][0];
    const unsigned short* Bb = &Bl[cur][0];
    bf16x8 af[2], bfr[8];
#pragma unroll
    for (int mi = 0; mi < 2; ++mi)
      af[mi] = *reinterpret_cast<const bf16x8*>(Ab + (w * 32 + mi * 16 + l15) * BK + l4 * 8);
#pragma unroll
    for (int ni = 0; ni < 8; ++ni)
      bfr[ni] = *reinterpret_cast<const bf16x8*>(Bb + (ni * 16 + l15) * BK + l4 * 8);
#pragma unroll
    for (int mi = 0; mi < 2; ++mi)
#pragma unroll
      for (int ni = 0; ni < 8; ++ni)
        acc[mi][ni] = __builtin_amdgcn_mfma_f32_16x16x32_bf16(af[mi], bfr[ni], acc[mi][ni], 0, 0, 0);
    __syncthreads();
    cur ^= 1;
  }

  if constexpr (MODE == 0) {
#pragma unroll
    for (int mi = 0; mi < 2; ++mi)
#pragma unroll
      for (int r = 0; r < 4; ++r) {
        size_t row = arow0 + w * 32 + mi * 16 + l4 * 4 + r;
#pragma unroll
        for (int ni = 0; ni < 8; ++ni)
          Cout[row * N + brow0 + ni * 16 + l15] = acc[mi][ni][r];
      }
  } else {
    bool isq = brow0 < 2048;
    bool isk = !isq && brow0 < 2560;
    int kvh = isq ? 0 : (int)((brow0 - (isk ? 2048 : 2560)) >> 7);
#pragma unroll
    for (int mi = 0; mi < 2; ++mi)
#pragma unroll
      for (int r = 0; r < 4; ++r) {
        size_t row = arow0 + w * 32 + mi * 16 + l4 * 4 + r;
        int bb = (int)(row >> 11), t = (int)(row & 2047);
        if (isq) {
#pragma unroll
          for (int ni = 0; ni < 4; ++ni) {
            float2 cs = rt[t * 64 + ni * 16 + l15];
            float a1 = acc[mi][ni][r], a2 = acc[mi][ni + 4][r];
            size_t col = brow0 + ni * 16 + l15;
            qb[row * 2048 + col]      = f2bf(a1 * cs.x - a2 * cs.y);
            qb[row * 2048 + col + 64] = f2bf(a2 * cs.x + a1 * cs.y);
          }
        } else if (isk) {
          int tile = t >> 6, kv = t & 63;
          size_t base = (size_t)((bb * 4 + kvh) * 32 + tile) * 8192;  // 16 planes x 64 kv x 8
#pragma unroll
          for (int ni = 0; ni < 4; ++ni) {
            int d = ni * 16 + l15;  // 0..63
            float2 cs = rt[t * 64 + d];
            float a1 = acc[mi][ni][r], a2 = acc[mi][ni + 4][r];
            int d2 = d + 64;
            kt2[base + (size_t)(d >> 3) * 512 + kv * 8 + (d & 7)]   = f2bf(a1 * cs.x - a2 * cs.y);
            kt2[base + (size_t)(d2 >> 3) * 512 + kv * 8 + (d2 & 7)] = f2bf(a2 * cs.x + a1 * cs.y);
          }
        } else {
          int tile = t >> 6, kv = t & 63;
          size_t base = (size_t)((bb * 4 + kvh) * 32 + tile) * 8192;  // 8 planes x 128 d x 8
#pragma unroll
          for (int ni = 0; ni < 8; ++ni) {
            int d = ni * 16 + l15;
            vt2[base + (size_t)(kv >> 3) * 1024 + d * 8 + (kv & 7)] = f2bf(acc[mi][ni][r]);
          }
        }
      }
  }
}

// ---------------- flash attention: ZERO LDS, ZERO barriers. 1 wave per block,
// 32 q-rows (q = lane&31). K and V read directly from fragment-ordered kt2/vt2
// as per-lane dwordx4 (L2-resident; GQA rep=4 reuse). 32x32 swapped QK^T,
// in-register exp2 softmax, P^T via v_permlane32_swap, defer-max.
// Grid 2048, antithetic pairing (nt sums to 33).
__global__ __launch_bounds__(64) void attn_kernel(const unsigned short* __restrict__ qb,
                                                  const unsigned short* __restrict__ kt2,
                                                  const unsigned short* __restrict__ vt2,
                                                  unsigned short* __restrict__ att) {
  int lane = threadIdx.x, l31 = lane & 31, hi = lane >> 5, h4 = hi * 4;
  int id = blockIdx.x;
  int u = id & 1023, half = id >> 10;
  int bh = u & 31, qq = u >> 5;          // qq 0..31
  int qi = half ? (63 - qq) : qq;        // 0..63, pair sums 63 -> nt sums 33
  int q0 = qi * 32;
  int b = bh >> 4, hd = bh & 15, kvh = hd >> 2;
  int ql = q0 + l31;

  // Q^T B-fragments, pre-scaled by log2(e)/sqrt(HD)
  bf16x8 qf[8];
  {
    const unsigned short* qp = qb + (size_t)(b * T_ + ql) * 2048 + hd * HD_ + hi * 8;
    const float scale = 0.08838834764831845f * 1.4426950408889634f;
#pragma unroll
    for (int df = 0; df < 8; ++df) {
      bf16x8 t = *reinterpret_cast<const bf16x8*>(qp + df * 16);
#pragma unroll
      for (int j = 0; j < 8; ++j) t[j] = (__bf16)((float)t[j] * scale);
      qf[df] = t;
    }
  }

  f32x16 o[4];  // O^T: d = dt*32 + (r&3)+8*(r>>2)+h4, col q=l31
#pragma unroll
  for (int dt = 0; dt < 4; ++dt)
#pragma unroll
    for (int r = 0; r < 16; ++r) o[dt][r] = 0.f;
  float mr = -1e30f, lr = 0.f;

  int nt = (qi >> 1) + 1;
  const unsigned short* kb = kt2 + (size_t)((b * 4 + kvh) * 32) * 8192;
  const unsigned short* vb = vt2 + (size_t)((b * 4 + kvh) * 32) * 8192;

  union Vc { uint4 u; bf16x8 v; };
  for (int kt = 0; kt < nt; ++kt) {
    int kv0 = kt * 64;
    const unsigned short* kbt = kb + (size_t)kt * 8192;
    const unsigned short* vbt = vb + (size_t)kt * 8192;

    // S^T = K Q^T; lane: q=l31, k = t2*32 + (r&3)+8(r>>2)+h4
    f32x16 s[2];
#pragma unroll
    for (int r = 0; r < 16; ++r) { s[0][r] = 0.f; s[1][r] = 0.f; }
    uint4 kx[4], ky[4];
#pragma unroll
    for (int df = 0; df < 4; ++df)
      kx[df] = *reinterpret_cast<const uint4*>(kbt + ((df * 2 + hi) * 64 + l31) * 8);
#pragma unroll
    for (int df = 0; df < 4; ++df)
      ky[df] = *reinterpret_cast<const uint4*>(kbt + (((df + 4) * 2 + hi) * 64 + l31) * 8);
    __builtin_amdgcn_s_setprio(1);
#pragma unroll
    for (int df = 0; df < 4; ++df) {
      Vc c; c.u = kx[df];
      s[0] = __builtin_amdgcn_mfma_f32_32x32x16_bf16(c.v, qf[df], s[0], 0, 0, 0);
    }
#pragma unroll
    for (int df = 0; df < 4; ++df)
      kx[df] = *reinterpret_cast<const uint4*>(kbt + ((df * 2 + hi) * 64 + 32 + l31) * 8);
#pragma unroll
    for (int df = 0; df < 4; ++df) {
      Vc c; c.u = ky[df];
      s[0] = __builtin_amdgcn_mfma_f32_32x32x16_bf16(c.v, qf[df + 4], s[0], 0, 0, 0);
    }
#pragma unroll
    for (int df = 0; df < 4; ++df)
      ky[df] = *reinterpret_cast<const uint4*>(kbt + (((df + 4) * 2 + hi) * 64 + 32 + l31) * 8);
#pragma unroll
    for (int df = 0; df < 4; ++df) {
      Vc c; c.u = kx[df];
      s[1] = __builtin_amdgcn_mfma_f32_32x32x16_bf16(c.v, qf[df], s[1], 0, 0, 0);
    }
#pragma unroll
    for (int df = 0; df < 4; ++df) {
      Vc c; c.u = ky[df];
      s[1] = __builtin_amdgcn_mfma_f32_32x32x16_bf16(c.v, qf[df + 4], s[1], 0, 0, 0);
    }
    __builtin_amdgcn_s_setprio(0);

    // mask only on diagonal tile, then row-max
    float rm = -1e30f;
    if (kv0 + 63 > q0) {
#pragma unroll
      for (int t2 = 0; t2 < 2; ++t2)
#pragma unroll
        for (int r = 0; r < 16; ++r) {
          float sv = s[t2][r];
          int kcol = kv0 + t2 * 32 + (r & 3) + 8 * (r >> 2) + h4;
          if (kcol > ql) sv = -1e30f;
          s[t2][r] = sv;
          rm = fmaxf(rm, sv);
        }
    } else {
#pragma unroll
      for (int t2 = 0; t2 < 2; ++t2)
#pragma unroll
        for (int r = 0; r < 16; ++r) rm = fmaxf(rm, s[t2][r]);
    }
    rm = fmaxf(rm, __shfl_xor(rm, 32));

    // defer-max (log2 units, THR=11)
    if (!__all(rm <= mr + 11.0f)) {
      float mnew = fmaxf(mr, rm);
      float alpha = exp2f(mr - mnew);
      mr = mnew;
      lr *= alpha;
#pragma unroll
      for (int dt = 0; dt < 4; ++dt)
#pragma unroll
        for (int r = 0; r < 16; ++r) o[dt][r] *= alpha;
    }

    // exp2 + per-lane partial sum
    float ps = 0.f;
#pragma unroll
    for (int t2 = 0; t2 < 2; ++t2)
#pragma unroll
      for (int r = 0; r < 16; ++r) {
        float p = exp2f(s[t2][r] - mr);
        s[t2][r] = p;
        ps += p;
      }
    lr += ps;

    // pack P to bf16 pairs
    unsigned pk[2][8];
#pragma unroll
    for (int t2 = 0; t2 < 2; ++t2)
#pragma unroll
      for (int i = 0; i < 8; ++i) {
        union { unsigned u32; __bf16 hh[2]; } pr;
        pr.hh[0] = (__bf16)s[t2][2 * i];
        pr.hh[1] = (__bf16)s[t2][2 * i + 1];
        pk[t2][i] = pr.u32;
      }

    // issue V loads for dt=0,1 (latency hides under permlane exchange)
    uint4 va[4], vc[4];
#pragma unroll
    for (int kf = 0; kf < 4; ++kf)
      va[kf] = *reinterpret_cast<const uint4*>(vbt + ((kf * 2 + hi) * 128 + l31) * 8);
#pragma unroll
    for (int kf = 0; kf < 4; ++kf)
      vc[kf] = *reinterpret_cast<const uint4*>(vbt + ((kf * 2 + hi) * 128 + 32 + l31) * 8);

    // P^T B-frags via permlane32_swap
    bf16x8 pb[4];
#pragma unroll
    for (int f = 0; f < 4; ++f) {
      int t2 = f >> 1, bq = (f & 1) * 4;
      union { bf16x8 v; unsigned d[4]; } fr;
#pragma unroll
      for (int p = 0; p < 2; ++p) {
        unsigned a = pk[t2][bq + p];
        unsigned bb2 = pk[t2][bq + 2 + p];
        asm("v_permlane32_swap_b32 %0, %1" : "+v"(a), "+v"(bb2));
        fr.d[p] = a;
        fr.d[2 + p] = bb2;
      }
      pb[f] = fr.v;
    }

    // O^T += V^T P^T, depth-2 reload
    __builtin_amdgcn_s_setprio(1);
#pragma unroll
    for (int kf = 0; kf < 4; ++kf) {
      Vc c; c.u = va[kf];
      o[0] = __builtin_amdgcn_mfma_f32_32x32x16_bf16(c.v, pb[kf], o[0], 0, 0, 0);
    }
#pragma unroll
    for (int kf = 0; kf < 4; ++kf)
      va[kf] = *reinterpret_cast<const uint4*>(vbt + ((kf * 2 + hi) * 128 + 64 + l31) * 8);
#pragma unroll
    for (int kf = 0; kf < 4; ++kf) {
      Vc c; c.u = vc[kf];
      o[1] = __builtin_amdgcn_mfma_f32_32x32x16_bf16(c.v, pb[kf], o[1], 0, 0, 0);
    }
#pragma unroll
    for (int kf = 0; kf < 4; ++kf)
      vc[kf] = *reinterpret_cast<const uint4*>(vbt + ((kf * 2 + hi) * 128 + 96 + l31) * 8);
#pragma unroll
    for (int kf = 0; kf < 4; ++kf) {
      Vc c; c.u = va[kf];
      o[2] = __builtin_amdgcn_mfma_f32_32x32x16_bf16(c.v, pb[kf], o[2], 0, 0, 0);
    }
#pragma unroll
    for (int kf = 0; kf < 4; ++kf) {
      Vc c; c.u = vc[kf];
      o[3] = __builtin_amdgcn_mfma_f32_32x32x16_bf16(c.v, pb[kf], o[3], 0, 0, 0);
    }
    __builtin_amdgcn_s_setprio(0);
  }

  // epilogue: finish l reduce, normalize, scatter O^T to att[q][d]
  float ls = lr + __shfl_xor(lr, 32);
  float inv = 1.f / ls;
  unsigned short* ob = att + (size_t)(b * T_ + ql) * C_ + hd * HD_;
#pragma unroll
  for (int dt = 0; dt < 4; ++dt)
#pragma unroll
    for (int r = 0; r < 16; ++r) {
      int d = dt * 32 + (r & 3) + 8 * (r >> 2) + h4;
      ob[d] = f2bf(o[dt][r] * inv);
    }
}

extern "C" void kernel_launch(void* const* d_in, const int* in_sizes, int n_in,
                              void* d_out, int out_size, void* d_ws, size_t ws_size,
                              hipStream_t stream) {
  const float* x  = (const float*)d_in[0];
  const float* Wq = (const float*)d_in[1];
  const float* Wk = (const float*)d_in[2];
  const float* Wv = (const float*)d_in[3];
  const float* Wp = (const float*)d_in[4];
  float* out = (float*)d_out;
  char* ws = (char*)d_ws;

  // workspace layout (bytes), total 63,963,136 + 4,194,304 = 63.96MB used
  unsigned short* xb  = (unsigned short*)(ws);              // 16MB  x bf16 (att aliases)
  unsigned short* wt  = (unsigned short*)(ws + 16777216);   // 20MB  Wq^T|Wk^T|Wv^T|Wp^T
  unsigned short* qb  = (unsigned short*)(ws + 37748736);   // 16MB  Q (rope'd) 4096x2048
  float2*         rt  = (float2*)(ws + 54525952);           // 1MB   cos/sin
  unsigned short* kt2 = (unsigned short*)(ws + 55574528);   // 4MB   K fragment-order
  unsigned short* vt2 = (unsigned short*)(ws + 59768832);   // 4MB   V fragment-order
  unsigned short* att = xb;                                 // alias: xb dead after GEMM1

  rope_table_kernel<<<T_, 64, 0, stream>>>(rt);
  convx_kernel<<<(M_ * C_ / 4 + 255) / 256, 256, 0, stream>>>(x, xb, M_ * C_ / 4);
  transpose_conv4_kernel<<<dim3(10240), 256, 0, stream>>>(Wq, Wk, Wv, Wp, wt);

  gemm_bf16<1><<<dim3(NQKV_ / 128, M_ / 128), 256, 0, stream>>>(
      xb, wt, nullptr, qb, kt2, vt2, rt, M_, NQKV_, C_);
  attn_kernel<<<dim3(2048), 64, 0, stream>>>(qb, kt2, vt2, att);
  gemm_bf16<0><<<dim3(C_ / 128, M_ / 128), 256, 0, stream>>>(
      att, wt + (size_t)3072 * 2048, out, nullptr, nullptr, nullptr, nullptr, M_, C_, C_);
}

// Round 12
// 241.414 us; speedup vs baseline: 1.1292x; 1.1292x over previous
//
#include <hip/hip_runtime.h>

#define B_ 2
#define T_ 2048
#define C_ 2048
#define NH_ 16
#define NKV_ 4
#define HD_ 128
#define M_ 4096          // B*T
#define NQKV_ 3072

typedef __bf16 bf16x8 __attribute__((ext_vector_type(8)));
typedef float f32x4 __attribute__((ext_vector_type(4)));
typedef float f32x16 __attribute__((ext_vector_type(16)));

__device__ __forceinline__ unsigned short f2bf(float f) {
  union { float f; unsigned u; } c{f};
  unsigned u = c.u + 0x7FFFu + ((c.u >> 16) & 1u);
  return (unsigned short)(u >> 16);
}

#define GLOAD_LDS16(g, l)                                        \
  __builtin_amdgcn_global_load_lds(                              \
      (const __attribute__((address_space(1))) void*)(g),        \
      (__attribute__((address_space(3))) void*)(l), 16, 0, 0)

// ---------------- RoPE cos/sin table: rt[t*64+i] = {cos,sin}(t * 10000^(-2i/128))
__global__ void rope_table_kernel(float2* __restrict__ rt) {
  int t = blockIdx.x, i = threadIdx.x;  // 2048 x 64
  float inv = powf(10000.f, -(float)(2 * i) / 128.f);
  float s, c;
  sincosf((float)t * inv, &s, &c);
  rt[t * 64 + i] = make_float2(c, s);
}

// ---------------- x f32 -> bf16 (vectorized)
__global__ void convx_kernel(const float* __restrict__ x, unsigned short* __restrict__ xb, int n4) {
  int i = blockIdx.x * blockDim.x + threadIdx.x;
  if (i >= n4) return;
  float4 v = reinterpret_cast<const float4*>(x)[i];
  union { ushort4 u; unsigned short s[4]; } o;
  o.s[0] = f2bf(v.x); o.s[1] = f2bf(v.y); o.s[2] = f2bf(v.z); o.s[3] = f2bf(v.w);
  reinterpret_cast<ushort4*>(xb)[i] = o.u;
}

// ---------------- all 4 weights (K x N, f32) -> Wt (N x K, bf16), one launch
__global__ void transpose_conv4_kernel(const float* __restrict__ Wq, const float* __restrict__ Wk,
                                       const float* __restrict__ Wv, const float* __restrict__ Wp,
                                       unsigned short* __restrict__ wt) {
  __shared__ float tile[32][33];
  int id = blockIdx.x;
  const float* W;
  unsigned short* Wt;
  int N, bx, by;
  if (id < 4096)      { W = Wq; Wt = wt;                          N = 2048; int u = id;        bx = u & 63; by = u >> 6; }
  else if (id < 5120) { W = Wk; Wt = wt + (size_t)2048 * 2048;    N = 512;  int u = id - 4096; bx = u & 15; by = u >> 4; }
  else if (id < 6144) { W = Wv; Wt = wt + (size_t)2560 * 2048;    N = 512;  int u = id - 5120; bx = u & 15; by = u >> 4; }
  else                { W = Wp; Wt = wt + (size_t)3072 * 2048;    N = 2048; int u = id - 6144; bx = u & 63; by = u >> 6; }
  const int K = 2048;
  bx *= 32; by *= 32;
  int tx = threadIdx.x & 31, ty = threadIdx.x >> 5;  // 32x8
#pragma unroll
  for (int r = 0; r < 32; r += 8)
    tile[ty + r][tx] = W[(size_t)(by + ty + r) * N + bx + tx];
  __syncthreads();
#pragma unroll
  for (int r = 0; r < 32; r += 8)
    Wt[(size_t)(bx + ty + r) * K + by + tx] = f2bf(tile[tx][ty + r]);
}

// ---------------- V slice of qkv -> vt2 in PV-fragment order:
// vt2[(((bh*32 + t)*8 + kv>>3)*128 + d)*8 + (kv&7)] = V[b][t*64 + kv][kvh][d]
__global__ void transpose_v_kernel(const unsigned short* __restrict__ qkv,
                                   unsigned short* __restrict__ vt2) {
  __shared__ unsigned short tile[64][136];
  int bt = blockIdx.x;           // bh*32 + t, bh = b*NKV+kvh
  int bh = bt >> 5, t = bt & 31;
  int b = bh >> 2, kvh = bh & 3;
  int tid = threadIdx.x;  // 256
#pragma unroll
  for (int p = 0; p < 4; ++p) {
    int kv = p * 16 + (tid >> 4);
    int c8 = (tid & 15) * 8;
    *reinterpret_cast<uint4*>(&tile[kv][c8]) = *reinterpret_cast<const uint4*>(
        &qkv[(size_t)(b * T_ + t * 64 + kv) * NQKV_ + 2560 + kvh * HD_ + c8]);
  }
  __syncthreads();
#pragma unroll
  for (int it = 0; it < 4; ++it) {
    int item = it * 256 + tid;       // (pk, d): pk = kv>>3
    int pk = item >> 7, d = item & 127;
    unsigned short tmp[8];
#pragma unroll
    for (int j = 0; j < 8; ++j) tmp[j] = tile[pk * 8 + j][d];
    *reinterpret_cast<uint4*>(&vt2[((size_t)(bt * 8 + pk) * 128 + d) * 8]) =
        *reinterpret_cast<uint4*>(tmp);
  }
}

// ---------------- bf16 GEMM: 128x128 tile, BK=32; wave = 32-row x 128-col strip.
// ROPE: fused RoPE on cols < 2560 (q,k heads; head width 128 == col-block).
template <typename OUT, bool ROPE>
__global__ __launch_bounds__(256) void gemm_bf16(const unsigned short* __restrict__ A,
                                                 const unsigned short* __restrict__ Bt,
                                                 OUT* __restrict__ Cm,
                                                 const float2* __restrict__ rt,
                                                 int M, int N, int K) {
  constexpr int BK = 32;
  __shared__ __align__(16) unsigned short Al[2][128 * BK];
  __shared__ __align__(16) unsigned short Bl[2][128 * BK];
  int tid = threadIdx.x, w = tid >> 6, lane = tid & 63;
  int l15 = lane & 15, l4 = lane >> 4;
  size_t arow0 = (size_t)blockIdx.y * 128;
  size_t brow0 = (size_t)blockIdx.x * 128;

  f32x4 acc[2][8];
#pragma unroll
  for (int mi = 0; mi < 2; ++mi)
#pragma unroll
    for (int ni = 0; ni < 8; ++ni) acc[mi][ni] = (f32x4){0.f, 0.f, 0.f, 0.f};

  auto stage = [&](int buf, int k0) {
#pragma unroll
    for (int i = 0; i < 2; ++i) {
      int c = i * 256 + w * 64 + lane;
      const unsigned short* g = A + (arow0 + (c >> 2)) * K + k0 + (c & 3) * 8;
      GLOAD_LDS16(g, &Al[buf][(i * 4 + w) * 512]);
    }
#pragma unroll
    for (int i = 0; i < 2; ++i) {
      int c = i * 256 + w * 64 + lane;
      const unsigned short* g = Bt + (brow0 + (c >> 2)) * K + k0 + (c & 3) * 8;
      GLOAD_LDS16(g, &Bl[buf][(i * 4 + w) * 512]);
    }
  };

  stage(0, 0);
  __syncthreads();
  int NT = K / BK, cur = 0;
  for (int kt = 0; kt < NT; ++kt) {
    if (kt + 1 < NT) stage(cur ^ 1, (kt + 1) * BK);
    const unsigned short* Ab = &Al[cur][0];
    const unsigned short* Bb = &Bl[cur][0];
    bf16x8 af[2], bfr[8];
#pragma unroll
    for (int mi = 0; mi < 2; ++mi)
      af[mi] = *reinterpret_cast<const bf16x8*>(Ab + (w * 32 + mi * 16 + l15) * BK + l4 * 8);
#pragma unroll
    for (int ni = 0; ni < 8; ++ni)
      bfr[ni] = *reinterpret_cast<const bf16x8*>(Bb + (ni * 16 + l15) * BK + l4 * 8);
#pragma unroll
    for (int mi = 0; mi < 2; ++mi)
#pragma unroll
      for (int ni = 0; ni < 8; ++ni)
        acc[mi][ni] = __builtin_amdgcn_mfma_f32_16x16x32_bf16(af[mi], bfr[ni], acc[mi][ni], 0, 0, 0);
    __syncthreads();
    cur ^= 1;
  }

  bool dorope = ROPE && (brow0 < 2560);  // q/k col-blocks only
#pragma unroll
  for (int mi = 0; mi < 2; ++mi)
#pragma unroll
    for (int r = 0; r < 4; ++r) {
      size_t row = arow0 + w * 32 + mi * 16 + l4 * 4 + r;
      if (dorope) {
        int t = (int)(row & (T_ - 1));
#pragma unroll
        for (int ni = 0; ni < 4; ++ni) {
          float2 cs = rt[t * 64 + ni * 16 + l15];
          float a1 = acc[mi][ni][r], a2 = acc[mi][ni + 4][r];
          size_t col = brow0 + ni * 16 + l15;
          Cm[row * N + col]      = f2bf(a1 * cs.x - a2 * cs.y);
          Cm[row * N + col + 64] = f2bf(a2 * cs.x + a1 * cs.y);
        }
      } else {
#pragma unroll
        for (int ni = 0; ni < 8; ++ni) {
          size_t col = brow0 + ni * 16 + l15;
          float v = acc[mi][ni][r];
          if constexpr (sizeof(OUT) == 4) Cm[row * N + col] = v;
          else                            Cm[row * N + col] = f2bf(v);
        }
      }
    }
}

// ---------------- flash attention: ONE wave per block (64 thr), 32 q-rows,
// KVBLK=64, GQA. ZERO barriers: wave-private 16KB K buffer via global_load_lds
// (vmcnt(0) between own stage and ds_read — other resident waves fill the
// SIMD during the wait). V direct from fragment-ordered vt2 (L2, R10-proven).
// 32x32 swapped QK^T, in-register exp2 softmax, permlane32_swap P-exchange,
// defer-max. Grid 2048, antithetic pairing + backfill.
__global__ __launch_bounds__(64) void attn_kernel(const unsigned short* __restrict__ qkv,
                                                  const unsigned short* __restrict__ vt2,
                                                  unsigned short* __restrict__ att) {
  __shared__ __align__(16) unsigned short Kl[64 * 128];  // 16KB, swizzled
  int lane = threadIdx.x, l31 = lane & 31, hi = lane >> 5, h4 = hi * 4;
  int id = blockIdx.x;
  int u = id & 1023, half = id >> 10;
  int bh = u & 31, qq = u >> 5;          // qq 0..31
  int qi = half ? (63 - qq) : qq;        // 0..63, pair nt sums to 33
  int q0 = qi * 32;
  int b = bh >> 4, hd = bh & 15, kvh = hd >> 2;
  int ql = q0 + l31;

  // Q^T B-fragments, pre-scaled by log2(e)/sqrt(HD)
  bf16x8 qf[8];
  {
    const unsigned short* qp = qkv + (size_t)(b * T_ + ql) * NQKV_ + hd * HD_ + hi * 8;
    const float scale = 0.08838834764831845f * 1.4426950408889634f;
#pragma unroll
    for (int df = 0; df < 8; ++df) {
      bf16x8 t = *reinterpret_cast<const bf16x8*>(qp + df * 16);
#pragma unroll
      for (int j = 0; j < 8; ++j) t[j] = (__bf16)((float)t[j] * scale);
      qf[df] = t;
    }
  }

  f32x16 o[4];  // O^T: d = dt*32 + (r&3)+8*(r>>2)+h4, col q=l31
#pragma unroll
  for (int dt = 0; dt < 4; ++dt)
#pragma unroll
    for (int r = 0; r < 16; ++r) o[dt][r] = 0.f;
  float mr = -1e30f, lr = 0.f;

  int nt = (qi >> 1) + 1;
  const unsigned short* vb = vt2 + (size_t)((b * 4 + kvh) * 32) * 8192;

  union Vc { uint4 u; bf16x8 v; };
  for (int kt = 0; kt < nt; ++kt) {
    int kv0 = kt * 64;

    // stage K(t) into private LDS: 16 x gload_lds16, pre-swizzled source
#pragma unroll
    for (int i = 0; i < 16; ++i) {
      int c = i * 64 + lane;               // 16B-chunk index 0..1023
      int g = c ^ ((c >> 4) & 7);          // row = c>>4
      const unsigned short* src =
          qkv + (size_t)(b * T_ + kv0 + (g >> 4)) * NQKV_ + C_ + kvh * HD_ + (g & 15) * 8;
      GLOAD_LDS16(src, &Kl[i * 512]);
    }
    asm volatile("s_waitcnt vmcnt(0)" ::: "memory");

    // S^T = K Q^T; lane: q=l31, k = t2*32 + (r&3)+8(r>>2)+h4
    f32x16 s[2];
#pragma unroll
    for (int r = 0; r < 16; ++r) { s[0][r] = 0.f; s[1][r] = 0.f; }
    __builtin_amdgcn_s_setprio(1);
#pragma unroll
    for (int t2 = 0; t2 < 2; ++t2)
#pragma unroll
      for (int df = 0; df < 8; ++df) {
        bf16x8 kf = *reinterpret_cast<const bf16x8*>(
            Kl + (((t2 * 32 + l31) * 128 + df * 16 + hi * 8) ^ ((l31 & 7) << 3)));
        s[t2] = __builtin_amdgcn_mfma_f32_32x32x16_bf16(kf, qf[df], s[t2], 0, 0, 0);
      }
    __builtin_amdgcn_s_setprio(0);

    // mask only on diagonal tile, then row-max
    float rm = -1e30f;
    if (kv0 + 63 > q0) {
#pragma unroll
      for (int t2 = 0; t2 < 2; ++t2)
#pragma unroll
        for (int r = 0; r < 16; ++r) {
          float sv = s[t2][r];
          int kcol = kv0 + t2 * 32 + (r & 3) + 8 * (r >> 2) + h4;
          if (kcol > ql) sv = -1e30f;
          s[t2][r] = sv;
          rm = fmaxf(rm, sv);
        }
    } else {
#pragma unroll
      for (int t2 = 0; t2 < 2; ++t2)
#pragma unroll
        for (int r = 0; r < 16; ++r) rm = fmaxf(rm, s[t2][r]);
    }
    rm = fmaxf(rm, __shfl_xor(rm, 32));

    // defer-max (log2 units, THR=11)
    if (!__all(rm <= mr + 11.0f)) {
      float mnew = fmaxf(mr, rm);
      float alpha = exp2f(mr - mnew);
      mr = mnew;
      lr *= alpha;
#pragma unroll
      for (int dt = 0; dt < 4; ++dt)
#pragma unroll
        for (int r = 0; r < 16; ++r) o[dt][r] *= alpha;
    }

    // exp2 + per-lane partial sum
    float ps = 0.f;
#pragma unroll
    for (int t2 = 0; t2 < 2; ++t2)
#pragma unroll
      for (int r = 0; r < 16; ++r) {
        float p = exp2f(s[t2][r] - mr);
        s[t2][r] = p;
        ps += p;
      }
    lr += ps;

    // pack P to bf16 pairs
    unsigned pk[2][8];
#pragma unroll
    for (int t2 = 0; t2 < 2; ++t2)
#pragma unroll
      for (int i = 0; i < 8; ++i) {
        union { unsigned u32; __bf16 hh[2]; } pr;
        pr.hh[0] = (__bf16)s[t2][2 * i];
        pr.hh[1] = (__bf16)s[t2][2 * i + 1];
        pk[t2][i] = pr.u32;
      }

    // issue V loads for dt=0,1 (L2; latency hides under permlane exchange)
    const unsigned short* vbt = vb + (size_t)kt * 8192;
    uint4 va[4], vc[4];
#pragma unroll
    for (int kf = 0; kf < 4; ++kf)
      va[kf] = *reinterpret_cast<const uint4*>(vbt + ((kf * 2 + hi) * 128 + l31) * 8);
#pragma unroll
    for (int kf = 0; kf < 4; ++kf)
      vc[kf] = *reinterpret_cast<const uint4*>(vbt + ((kf * 2 + hi) * 128 + 32 + l31) * 8);

    // P^T B-frags via permlane32_swap
    bf16x8 pb[4];
#pragma unroll
    for (int f = 0; f < 4; ++f) {
      int t2 = f >> 1, bq = (f & 1) * 4;
      union { bf16x8 v; unsigned d[4]; } fr;
#pragma unroll
      for (int p = 0; p < 2; ++p) {
        unsigned a = pk[t2][bq + p];
        unsigned bb2 = pk[t2][bq + 2 + p];
        asm("v_permlane32_swap_b32 %0, %1" : "+v"(a), "+v"(bb2));
        fr.d[p] = a;
        fr.d[2 + p] = bb2;
      }
      pb[f] = fr.v;
    }

    // O^T += V^T P^T, depth-2 reload
    __builtin_amdgcn_s_setprio(1);
#pragma unroll
    for (int kf = 0; kf < 4; ++kf) {
      Vc c; c.u = va[kf];
      o[0] = __builtin_amdgcn_mfma_f32_32x32x16_bf16(c.v, pb[kf], o[0], 0, 0, 0);
    }
#pragma unroll
    for (int kf = 0; kf < 4; ++kf)
      va[kf] = *reinterpret_cast<const uint4*>(vbt + ((kf * 2 + hi) * 128 + 64 + l31) * 8);
#pragma unroll
    for (int kf = 0; kf < 4; ++kf) {
      Vc c; c.u = vc[kf];
      o[1] = __builtin_amdgcn_mfma_f32_32x32x16_bf16(c.v, pb[kf], o[1], 0, 0, 0);
    }
#pragma unroll
    for (int kf = 0; kf < 4; ++kf)
      vc[kf] = *reinterpret_cast<const uint4*>(vbt + ((kf * 2 + hi) * 128 + 96 + l31) * 8);
#pragma unroll
    for (int kf = 0; kf < 4; ++kf) {
      Vc c; c.u = va[kf];
      o[2] = __builtin_amdgcn_mfma_f32_32x32x16_bf16(c.v, pb[kf], o[2], 0, 0, 0);
    }
#pragma unroll
    for (int kf = 0; kf < 4; ++kf) {
      Vc c; c.u = vc[kf];
      o[3] = __builtin_amdgcn_mfma_f32_32x32x16_bf16(c.v, pb[kf], o[3], 0, 0, 0);
    }
    __builtin_amdgcn_s_setprio(0);
  }

  // epilogue: finish l reduce, normalize, scatter O^T to att[q][d]
  float ls = lr + __shfl_xor(lr, 32);
  float inv = 1.f / ls;
  unsigned short* ob = att + (size_t)(b * T_ + ql) * C_ + hd * HD_;
#pragma unroll
  for (int dt = 0; dt < 4; ++dt)
#pragma unroll
    for (int r = 0; r < 16; ++r) {
      int d = dt * 32 + (r & 3) + 8 * (r >> 2) + h4;
      ob[d] = f2bf(o[dt][r] * inv);
    }
}

extern "C" void kernel_launch(void* const* d_in, const int* in_sizes, int n_in,
                              void* d_out, int out_size, void* d_ws, size_t ws_size,
                              hipStream_t stream) {
  const float* x  = (const float*)d_in[0];
  const float* Wq = (const float*)d_in[1];
  const float* Wk = (const float*)d_in[2];
  const float* Wv = (const float*)d_in[3];
  const float* Wp = (const float*)d_in[4];
  float* out = (float*)d_out;
  char* ws = (char*)d_ws;

  // workspace layout (bytes)
  unsigned short* xb  = (unsigned short*)(ws);              // 16MB  x bf16 (att aliases)
  unsigned short* wt  = (unsigned short*)(ws + 16777216);   // 20MB  Wq^T|Wk^T|Wv^T|Wp^T
  unsigned short* qkv = (unsigned short*)(ws + 37748736);   // 24MB  q(rope)|k(rope)|v
  float2*         rt  = (float2*)(ws + 62914560);           // 1MB   cos/sin
  unsigned short* vt2 = (unsigned short*)(ws + 63963136);   // 4MB   V fragment-order
  unsigned short* att = xb;                                 // alias: xb dead after GEMM1

  rope_table_kernel<<<T_, 64, 0, stream>>>(rt);
  convx_kernel<<<(M_ * C_ / 4 + 255) / 256, 256, 0, stream>>>(x, xb, M_ * C_ / 4);
  transpose_conv4_kernel<<<dim3(10240), 256, 0, stream>>>(Wq, Wk, Wv, Wp, wt);

  gemm_bf16<unsigned short, true><<<dim3(NQKV_ / 128, M_ / 128), 256, 0, stream>>>(
      xb, wt, qkv, rt, M_, NQKV_, C_);
  transpose_v_kernel<<<dim3(256), 256, 0, stream>>>(qkv, vt2);
  attn_kernel<<<dim3(2048), 64, 0, stream>>>(qkv, vt2, att);
  gemm_bf16<float, false><<<dim3(C_ / 128, M_ / 128), 256, 0, stream>>>(
      att, wt + (size_t)3072 * 2048, out, nullptr, M_, C_, C_);
}

// Round 13
// 233.689 us; speedup vs baseline: 1.1665x; 1.0331x over previous
//
#include <hip/hip_runtime.h>

#define B_ 2
#define T_ 2048
#define C_ 2048
#define NH_ 16
#define NKV_ 4
#define HD_ 128
#define M_ 4096          // B*T
#define NQKV_ 3072

typedef __bf16 bf16x8 __attribute__((ext_vector_type(8)));
typedef float f32x4 __attribute__((ext_vector_type(4)));
typedef float f32x16 __attribute__((ext_vector_type(16)));

__device__ __forceinline__ unsigned short f2bf(float f) {
  union { float f; unsigned u; } c{f};
  unsigned u = c.u + 0x7FFFu + ((c.u >> 16) & 1u);
  return (unsigned short)(u >> 16);
}

#define GLOAD_LDS16(g, l)                                        \
  __builtin_amdgcn_global_load_lds(                              \
      (const __attribute__((address_space(1))) void*)(g),        \
      (__attribute__((address_space(3))) void*)(l), 16, 0, 0)

// ---------------- RoPE cos/sin table: rt[t*64+i] = {cos,sin}(t * 10000^(-2i/128))
__global__ void rope_table_kernel(float2* __restrict__ rt) {
  int t = blockIdx.x, i = threadIdx.x;  // 2048 x 64
  float inv = powf(10000.f, -(float)(2 * i) / 128.f);
  float s, c;
  sincosf((float)t * inv, &s, &c);
  rt[t * 64 + i] = make_float2(c, s);
}

// ---------------- x f32 -> bf16 (vectorized)
__global__ void convx_kernel(const float* __restrict__ x, unsigned short* __restrict__ xb, int n4) {
  int i = blockIdx.x * blockDim.x + threadIdx.x;
  if (i >= n4) return;
  float4 v = reinterpret_cast<const float4*>(x)[i];
  union { ushort4 u; unsigned short s[4]; } o;
  o.s[0] = f2bf(v.x); o.s[1] = f2bf(v.y); o.s[2] = f2bf(v.z); o.s[3] = f2bf(v.w);
  reinterpret_cast<ushort4*>(xb)[i] = o.u;
}

// ---------------- all 4 weights (K x N, f32) -> Wt (N x K, bf16), one launch
__global__ void transpose_conv4_kernel(const float* __restrict__ Wq, const float* __restrict__ Wk,
                                       const float* __restrict__ Wv, const float* __restrict__ Wp,
                                       unsigned short* __restrict__ wt) {
  __shared__ float tile[32][33];
  int id = blockIdx.x;
  const float* W;
  unsigned short* Wt;
  int N, bx, by;
  if (id < 4096)      { W = Wq; Wt = wt;                          N = 2048; int u = id;        bx = u & 63; by = u >> 6; }
  else if (id < 5120) { W = Wk; Wt = wt + (size_t)2048 * 2048;    N = 512;  int u = id - 4096; bx = u & 15; by = u >> 4; }
  else if (id < 6144) { W = Wv; Wt = wt + (size_t)2560 * 2048;    N = 512;  int u = id - 5120; bx = u & 15; by = u >> 4; }
  else                { W = Wp; Wt = wt + (size_t)3072 * 2048;    N = 2048; int u = id - 6144; bx = u & 63; by = u >> 6; }
  const int K = 2048;
  bx *= 32; by *= 32;
  int tx = threadIdx.x & 31, ty = threadIdx.x >> 5;  // 32x8
#pragma unroll
  for (int r = 0; r < 32; r += 8)
    tile[ty + r][tx] = W[(size_t)(by + ty + r) * N + bx + tx];
  __syncthreads();
#pragma unroll
  for (int r = 0; r < 32; r += 8)
    Wt[(size_t)(bx + ty + r) * K + by + tx] = f2bf(tile[tx][ty + r]);
}

// ---------------- V slice of qkv -> vt[(b*NKV+kvh)*HD + d][t]  (bf16 transpose)
__global__ void transpose_v_kernel(const unsigned short* __restrict__ qkv,
                                   unsigned short* __restrict__ vt) {
  __shared__ unsigned short tile[32][33];
  int bh = blockIdx.z;                 // b*NKV + kvh
  int b = bh >> 2, kvh = bh & 3;
  int t0 = blockIdx.x * 32, d0 = blockIdx.y * 32;
  int tx = threadIdx.x & 31, ty = threadIdx.x >> 5;
#pragma unroll
  for (int r = 0; r < 32; r += 8)
    tile[ty + r][tx] = qkv[(size_t)(b * T_ + t0 + ty + r) * NQKV_ + 2560 + kvh * HD_ + d0 + tx];
  __syncthreads();
#pragma unroll
  for (int r = 0; r < 32; r += 8)
    vt[(size_t)(bh * HD_ + d0 + ty + r) * T_ + t0 + tx] = tile[tx][ty + r];
}

// ---------------- 8-phase bf16 GEMM (T3+T4+T5): C(MxN) = A(MxK)*Bt(NxK)^T.
// Tile BM x 256, BK=64 split in 2 K-halves; 8 waves (4M x 2N), 512 thr.
// Per iter: 2 K-tiles, 8 phases {ds_read subtile | stage 1 half | bar |
// lgkmcnt(0) | MFMA | [vmcnt(N) at ph4/ph8] | bar}. vmcnt never 0 in-loop.
// LDS halves XOR-swizzled (chunk ^= row&3) via pre-swizzled global source.
// ROPE: fused RoPE on head-blocks < 2560 (wave covers exactly one head).
template <int BM, typename OUT, bool ROPE>
__global__ __launch_bounds__(512, 1) void gemm8p(const unsigned short* __restrict__ A,
                                                 const unsigned short* __restrict__ Bt,
                                                 OUT* __restrict__ Cm,
                                                 const float2* __restrict__ rt,
                                                 int M, int N, int K) {
  constexpr int MR = BM / 64;  // A-frags per wave: 4 (BM=256) or 2 (BM=128)
  __shared__ __align__(16) unsigned short As[2][2][BM * 32];
  __shared__ __align__(16) unsigned short Bs[2][2][256 * 32];
  int tid = threadIdx.x, wid = tid >> 6, lane = tid & 63;
  int l15 = lane & 15, l4 = lane >> 4;
  int wr = wid >> 1, wc = wid & 1;  // 4M x 2N
  size_t arow0 = (size_t)blockIdx.y * BM;
  size_t brow0 = (size_t)blockIdx.x * 256;
  int tmax = K / 64 - 1;

  f32x4 acc[MR][8];
#pragma unroll
  for (int m = 0; m < MR; ++m)
#pragma unroll
    for (int n = 0; n < 8; ++n) acc[m][n] = (f32x4){0.f, 0.f, 0.f, 0.f};

  auto stageA = [&](int slot, int kh, int tile) {
    int k0 = tile * 64 + kh * 32;
    constexpr int NLD = (BM * 32 * 2) / (512 * 16);  // 2 (BM=256) or 1 (BM=128)
#pragma unroll
    for (int i = 0; i < NLD; ++i) {
      int c = i * 512 + wid * 64 + lane;
      int rg = c >> 2, cg = (c & 3) ^ (rg & 3);
      const unsigned short* g = A + (arow0 + rg) * K + k0 + cg * 8;
      GLOAD_LDS16(g, &As[slot][kh][c * 8]);
    }
  };
  auto stageB = [&](int slot, int kh, int tile) {
    int k0 = tile * 64 + kh * 32;
#pragma unroll
    for (int i = 0; i < 2; ++i) {
      int c = i * 512 + wid * 64 + lane;
      int rg = c >> 2, cg = (c & 3) ^ (rg & 3);
      const unsigned short* g = Bt + (brow0 + rg) * K + k0 + cg * 8;
      GLOAD_LDS16(g, &Bs[slot][kh][c * 8]);
    }
  };

  // prologue: tile0 {A00,B00,A01,B01}, tile1 {A10,B10,A11}; allow last 3 halves
  stageA(0, 0, 0); stageB(0, 0, 0); stageA(0, 1, 0); stageB(0, 1, 0);
  stageA(1, 0, 1); stageB(1, 0, 1); stageA(1, 1, 1);
  if constexpr (BM == 256) asm volatile("s_waitcnt vmcnt(6)" ::: "memory");
  else                     asm volatile("s_waitcnt vmcnt(4)" ::: "memory");
  __builtin_amdgcn_s_barrier();
  __builtin_amdgcn_sched_barrier(0);

  int NT2 = K / 128;
  for (int it = 0; it < NT2; ++it) {
    int t2 = it * 2;
#pragma unroll
    for (int tt = 0; tt < 2; ++tt) {
      bf16x8 af[MR];
#pragma unroll
      for (int kh = 0; kh < 2; ++kh) {
#pragma unroll
        for (int nh = 0; nh < 2; ++nh) {
          int p = tt * 4 + kh * 2 + nh + 1;  // 1..8 (constant under unroll)
          // ds_read subtile: A frags once per (tt,kh); B frags per phase
          if (nh == 0) {
#pragma unroll
            for (int m = 0; m < MR; ++m) {
              int r = wr * (MR * 16) + m * 16 + l15;
              af[m] = *reinterpret_cast<const bf16x8*>(
                  &As[tt][kh][r * 32 + ((l4 ^ (r & 3)) * 8)]);
            }
          }
          bf16x8 bf[4];
#pragma unroll
          for (int j = 0; j < 4; ++j) {
            int r = wc * 128 + (nh * 4 + j) * 16 + l15;
            bf[j] = *reinterpret_cast<const bf16x8*>(
                &Bs[tt][kh][r * 32 + ((l4 ^ (r & 3)) * 8)]);
          }
          // stage one half per phase (ledger-verified rotation, tail-clamped)
          if (p == 1) stageB(1, 1, t2 + 1);
          if (p == 2) stageA(0, 0, t2 + 2 <= tmax ? t2 + 2 : tmax);
          if (p == 3) stageB(0, 0, t2 + 2 <= tmax ? t2 + 2 : tmax);
          if (p == 4) stageA(0, 1, t2 + 2 <= tmax ? t2 + 2 : tmax);
          if (p == 5) stageB(0, 1, t2 + 2 <= tmax ? t2 + 2 : tmax);
          if (p == 6) stageA(1, 0, t2 + 3 <= tmax ? t2 + 3 : tmax);
          if (p == 7) stageB(1, 0, t2 + 3 <= tmax ? t2 + 3 : tmax);
          if (p == 8) stageA(1, 1, t2 + 3 <= tmax ? t2 + 3 : tmax);

          __builtin_amdgcn_s_barrier();
          asm volatile("s_waitcnt lgkmcnt(0)" ::: "memory");
          __builtin_amdgcn_sched_barrier(0);
          __builtin_amdgcn_s_setprio(1);
#pragma unroll
          for (int m = 0; m < MR; ++m)
#pragma unroll
            for (int j = 0; j < 4; ++j)
              acc[m][nh * 4 + j] = __builtin_amdgcn_mfma_f32_16x16x32_bf16(
                  af[m], bf[j], acc[m][nh * 4 + j], 0, 0, 0);
          __builtin_amdgcn_s_setprio(0);
          if (p == 4 || p == 8) {
            if constexpr (BM == 256) asm volatile("s_waitcnt vmcnt(6)" ::: "memory");
            else                     asm volatile("s_waitcnt vmcnt(4)" ::: "memory");
          }
          __builtin_amdgcn_s_barrier();
          __builtin_amdgcn_sched_barrier(0);
        }
      }
    }
  }

  bool dorope = ROPE && (brow0 + wc * 128 < 2560);
#pragma unroll
  for (int m = 0; m < MR; ++m)
#pragma unroll
    for (int r = 0; r < 4; ++r) {
      size_t row = arow0 + wr * (MR * 16) + m * 16 + l4 * 4 + r;
      if (dorope) {
        int t = (int)(row & (T_ - 1));
#pragma unroll
        for (int n = 0; n < 4; ++n) {
          float2 cs = rt[t * 64 + n * 16 + l15];
          float a1 = acc[m][n][r], a2 = acc[m][n + 4][r];
          size_t col = brow0 + wc * 128 + n * 16 + l15;
          Cm[row * N + col]      = f2bf(a1 * cs.x - a2 * cs.y);
          Cm[row * N + col + 64] = f2bf(a2 * cs.x + a1 * cs.y);
        }
      } else {
#pragma unroll
        for (int n = 0; n < 8; ++n) {
          size_t col = brow0 + wc * 128 + n * 16 + l15;
          float v = acc[m][n][r];
          if constexpr (sizeof(OUT) == 4) Cm[row * N + col] = v;
          else                            Cm[row * N + col] = f2bf(v);
        }
      }
    }
}

// ---------------- flash attention (R8, proven 86.5us): QBLK=128 (4 waves x 32
// q-rows), KVBLK=64, GQA. 32x32 swapped QK^T, in-register softmax (exp2), P^T
// via xor-32 exchange. Prefetch-at-top, ONE barrier/iter. Balanced 1D grid,
// swizzled LDS, defer-max, diagonal-only masking, setprio.
__global__ __launch_bounds__(256, 2) void attn_kernel(const unsigned short* __restrict__ qkv,
                                                      const unsigned short* __restrict__ vt,
                                                      unsigned short* __restrict__ att) {
  constexpr int KB = 64;
  __shared__ __align__(16) unsigned short Kl[2][KB * 128];   // [kv][d] 32KB, swizzled
  __shared__ __align__(16) unsigned short Vl[2][128 * KB];   // [d][kv] 32KB, swizzled
  int tid = threadIdx.x, w = tid >> 6, lane = tid & 63;
  int l31 = lane & 31, hi = lane >> 5;
  int h4 = hi * 4;

  int id = blockIdx.x;
  int u = id & 255, half = id >> 8;
  int bh = u & 31;
  int qh = u >> 5;                       // 0..7
  int qi = half ? (15 - qh) : qh;        // 0..15
  int q0 = qi * 128;
  int b = bh >> 4, hd = bh & 15, kvh = hd >> 2;
  int qr0 = q0 + w * 32;   // this wave's first q row
  int ql = qr0 + l31;      // this lane's q row

  bf16x8 qf[8];
  {
    const unsigned short* qb = qkv + (size_t)(b * T_ + ql) * NQKV_ + hd * HD_ + hi * 8;
    const float scale = 0.08838834764831845f * 1.4426950408889634f;
#pragma unroll
    for (int df = 0; df < 8; ++df) {
      bf16x8 t = *reinterpret_cast<const bf16x8*>(qb + df * 16);
#pragma unroll
      for (int j = 0; j < 8; ++j) t[j] = (__bf16)((float)t[j] * scale);
      qf[df] = t;
    }
  }

  f32x16 o[4];
#pragma unroll
  for (int dt = 0; dt < 4; ++dt)
#pragma unroll
    for (int r = 0; r < 16; ++r) o[dt][r] = 0.f;
  float mr = -1e30f, lr = 0.f;

  auto stage = [&](int buf, int kv0) {
#pragma unroll
    for (int i = 0; i < 4; ++i) {  // K tile: chunk c ^= (row&7), row = c>>4
      int c = (i * 4 + w) * 64 + lane;
      int g = c ^ ((c >> 4) & 7);
      const unsigned short* src =
          qkv + (size_t)(b * T_ + kv0 + (g >> 4)) * NQKV_ + C_ + kvh * HD_ + (g & 15) * 8;
      GLOAD_LDS16(src, &Kl[buf][(i * 4 + w) * 512]);
    }
#pragma unroll
    for (int i = 0; i < 4; ++i) {  // V^T tile: chunk c ^= (row&7), row = c>>3
      int c = (i * 4 + w) * 64 + lane;
      int g = c ^ ((c >> 3) & 7);
      const unsigned short* src =
          vt + (size_t)((b * NKV_ + kvh) * HD_ + (g >> 3)) * T_ + kv0 + (g & 7) * 8;
      GLOAD_LDS16(src, &Vl[buf][(i * 4 + w) * 512]);
    }
  };

  int nt = q0 / KB + 2;
  stage(0, 0);
  __syncthreads();
  int cur = 0;
  for (int kt = 0; kt < nt; ++kt) {
    int kv0 = kt * KB;
    if (kt + 1 < nt) stage(cur ^ 1, kv0 + KB);

    if (kv0 <= qr0 + 31) {
      f32x16 s[2];
#pragma unroll
      for (int r = 0; r < 16; ++r) { s[0][r] = 0.f; s[1][r] = 0.f; }
      const unsigned short* Kb = &Kl[cur][0];
      __builtin_amdgcn_s_setprio(1);
#pragma unroll
      for (int t2 = 0; t2 < 2; ++t2)
#pragma unroll
        for (int df = 0; df < 8; ++df) {
          bf16x8 kf = *reinterpret_cast<const bf16x8*>(
              Kb + (((t2 * 32 + l31) * 128 + df * 16 + hi * 8) ^ ((l31 & 7) << 3)));
          s[t2] = __builtin_amdgcn_mfma_f32_32x32x16_bf16(kf, qf[df], s[t2], 0, 0, 0);
        }
      __builtin_amdgcn_s_setprio(0);

      float rm = -1e30f;
      if ((kv0 + KB - 1) > qr0) {
#pragma unroll
        for (int t2 = 0; t2 < 2; ++t2)
#pragma unroll
          for (int r = 0; r < 16; ++r) {
            float sv = s[t2][r];
            int kcol = kv0 + t2 * 32 + (r & 3) + 8 * (r >> 2) + h4;
            if (kcol > ql) sv = -1e30f;
            s[t2][r] = sv;
            rm = fmaxf(rm, sv);
          }
      } else {
#pragma unroll
        for (int t2 = 0; t2 < 2; ++t2)
#pragma unroll
          for (int r = 0; r < 16; ++r) rm = fmaxf(rm, s[t2][r]);
      }
      rm = fmaxf(rm, __shfl_xor(rm, 32));

      if (!__all(rm <= mr + 11.0f)) {
        float mnew = fmaxf(mr, rm);
        float alpha = exp2f(mr - mnew);
        mr = mnew;
        lr *= alpha;
#pragma unroll
        for (int dt = 0; dt < 4; ++dt)
#pragma unroll
          for (int r = 0; r < 16; ++r) o[dt][r] *= alpha;
      }

      float ps = 0.f;
#pragma unroll
      for (int t2 = 0; t2 < 2; ++t2)
#pragma unroll
        for (int r = 0; r < 16; ++r) {
          float p = exp2f(s[t2][r] - mr);
          s[t2][r] = p;
          ps += p;
        }
      lr += ps;

      unsigned pk[2][8];
#pragma unroll
      for (int t2 = 0; t2 < 2; ++t2)
#pragma unroll
        for (int i = 0; i < 8; ++i) {
          union { unsigned u32; __bf16 hh[2]; } pr;
          pr.hh[0] = (__bf16)s[t2][2 * i];
          pr.hh[1] = (__bf16)s[t2][2 * i + 1];
          pk[t2][i] = pr.u32;
        }

      bf16x8 pb[4];
#pragma unroll
      for (int f = 0; f < 4; ++f) {
        int t2 = f >> 1, bq = (f & 1) * 4;
        union { bf16x8 v; unsigned d[4]; } fr;
#pragma unroll
        for (int p = 0; p < 2; ++p) {
          unsigned uu = pk[t2][bq + p];
          unsigned ww = pk[t2][bq + 2 + p];
          unsigned us = (unsigned)__shfl_xor((int)uu, 32);
          unsigned ws = (unsigned)__shfl_xor((int)ww, 32);
          fr.d[p]     = hi ? ws : uu;
          fr.d[2 + p] = hi ? ww : us;
        }
        pb[f] = fr.v;
      }

      const unsigned short* Vb = &Vl[cur][0];
      __builtin_amdgcn_s_setprio(1);
#pragma unroll
      for (int dt = 0; dt < 4; ++dt)
#pragma unroll
        for (int kf = 0; kf < 4; ++kf) {
          bf16x8 vf = *reinterpret_cast<const bf16x8*>(
              Vb + (((dt * 32 + l31) * KB + kf * 16 + hi * 8) ^ ((l31 & 7) << 3)));
          o[dt] = __builtin_amdgcn_mfma_f32_32x32x16_bf16(vf, pb[kf], o[dt], 0, 0, 0);
        }
      __builtin_amdgcn_s_setprio(0);
    }

    __syncthreads();
    cur ^= 1;
  }

  float ls = lr + __shfl_xor(lr, 32);
  float inv = 1.f / ls;
  unsigned short* ob = att + (size_t)(b * T_ + ql) * C_ + hd * HD_;
#pragma unroll
  for (int dt = 0; dt < 4; ++dt)
#pragma unroll
    for (int r = 0; r < 16; ++r) {
      int d = dt * 32 + (r & 3) + 8 * (r >> 2) + h4;
      ob[d] = f2bf(o[dt][r] * inv);
    }
}

extern "C" void kernel_launch(void* const* d_in, const int* in_sizes, int n_in,
                              void* d_out, int out_size, void* d_ws, size_t ws_size,
                              hipStream_t stream) {
  const float* x  = (const float*)d_in[0];
  const float* Wq = (const float*)d_in[1];
  const float* Wk = (const float*)d_in[2];
  const float* Wv = (const float*)d_in[3];
  const float* Wp = (const float*)d_in[4];
  float* out = (float*)d_out;
  char* ws = (char*)d_ws;

  // workspace layout (bytes); total 68,157,440
  unsigned short* xb  = (unsigned short*)(ws);              // 16MB  x bf16 (att aliases)
  unsigned short* wt  = (unsigned short*)(ws + 16777216);   // 20MB  Wq^T|Wk^T|Wv^T|Wp^T
  unsigned short* qkv = (unsigned short*)(ws + 37748736);   // 24MB  q(rope)|k(rope)|v
  float2*         rt  = (float2*)(ws + 62914560);           // 1MB   cos/sin
  unsigned short* vt  = (unsigned short*)(ws + 63963136);   // 4MB   V d-major [bh*HD+d][t]
  unsigned short* att = xb;                                 // alias: xb dead after GEMM1

  rope_table_kernel<<<T_, 64, 0, stream>>>(rt);
  convx_kernel<<<(M_ * C_ / 4 + 255) / 256, 256, 0, stream>>>(x, xb, M_ * C_ / 4);
  transpose_conv4_kernel<<<dim3(10240), 256, 0, stream>>>(Wq, Wk, Wv, Wp, wt);

  gemm8p<256, unsigned short, true><<<dim3(NQKV_ / 256, M_ / 256), 512, 0, stream>>>(
      xb, wt, qkv, rt, M_, NQKV_, C_);
  transpose_v_kernel<<<dim3(T_ / 32, HD_ / 32, B_ * NKV_), 256, 0, stream>>>(qkv, vt);
  attn_kernel<<<dim3(512), 256, 0, stream>>>(qkv, vt, att);
  gemm8p<128, float, false><<<dim3(C_ / 256, M_ / 128), 512, 0, stream>>>(
      att, wt + (size_t)3072 * 2048, out, nullptr, M_, C_, C_);
}

// Round 14
// 215.713 us; speedup vs baseline: 1.2637x; 1.0833x over previous
//
#include <hip/hip_runtime.h>

#define B_ 2
#define T_ 2048
#define C_ 2048
#define NH_ 16
#define NKV_ 4
#define HD_ 128
#define M_ 4096          // B*T
#define NQKV_ 3072

typedef __bf16 bf16x8 __attribute__((ext_vector_type(8)));
typedef float f32x4 __attribute__((ext_vector_type(4)));
typedef float f32x16 __attribute__((ext_vector_type(16)));

__device__ __forceinline__ unsigned short f2bf(float f) {
  union { float f; unsigned u; } c{f};
  unsigned u = c.u + 0x7FFFu + ((c.u >> 16) & 1u);
  return (unsigned short)(u >> 16);
}

#define GLOAD_LDS16(g, l)                                        \
  __builtin_amdgcn_global_load_lds(                              \
      (const __attribute__((address_space(1))) void*)(g),        \
      (__attribute__((address_space(3))) void*)(l), 16, 0, 0)

// asm ds_read_b128: opaque to alias analysis -> no compiler-inserted vmcnt
// drains against outstanding global_load_lds (rule #18 pattern: caller must
// fence with lgkmcnt(0) + sched_barrier(0) before consuming).
__device__ __forceinline__ bf16x8 ldsread128(const unsigned short* p) {
  uint4 d;
  asm volatile("ds_read_b128 %0, %1"
               : "=v"(d)
               : "v"((const __attribute__((address_space(3))) void*)p));
  union { uint4 u; bf16x8 v; } c;
  c.u = d;
  return c.v;
}

// ---------------- RoPE cos/sin table: rt[t*64+i] = {cos,sin}(t * 10000^(-2i/128))
__global__ void rope_table_kernel(float2* __restrict__ rt) {
  int t = blockIdx.x, i = threadIdx.x;  // 2048 x 64
  float inv = powf(10000.f, -(float)(2 * i) / 128.f);
  float s, c;
  sincosf((float)t * inv, &s, &c);
  rt[t * 64 + i] = make_float2(c, s);
}

// ---------------- x f32 -> bf16 (vectorized)
__global__ void convx_kernel(const float* __restrict__ x, unsigned short* __restrict__ xb, int n4) {
  int i = blockIdx.x * blockDim.x + threadIdx.x;
  if (i >= n4) return;
  float4 v = reinterpret_cast<const float4*>(x)[i];
  union { ushort4 u; unsigned short s[4]; } o;
  o.s[0] = f2bf(v.x); o.s[1] = f2bf(v.y); o.s[2] = f2bf(v.z); o.s[3] = f2bf(v.w);
  reinterpret_cast<ushort4*>(xb)[i] = o.u;
}

// ---------------- all 4 weights (K x N, f32) -> Wt (N x K, bf16), one launch
__global__ void transpose_conv4_kernel(const float* __restrict__ Wq, const float* __restrict__ Wk,
                                       const float* __restrict__ Wv, const float* __restrict__ Wp,
                                       unsigned short* __restrict__ wt) {
  __shared__ float tile[32][33];
  int id = blockIdx.x;
  const float* W;
  unsigned short* Wt;
  int N, bx, by;
  if (id < 4096)      { W = Wq; Wt = wt;                          N = 2048; int u = id;        bx = u & 63; by = u >> 6; }
  else if (id < 5120) { W = Wk; Wt = wt + (size_t)2048 * 2048;    N = 512;  int u = id - 4096; bx = u & 15; by = u >> 4; }
  else if (id < 6144) { W = Wv; Wt = wt + (size_t)2560 * 2048;    N = 512;  int u = id - 5120; bx = u & 15; by = u >> 4; }
  else                { W = Wp; Wt = wt + (size_t)3072 * 2048;    N = 2048; int u = id - 6144; bx = u & 63; by = u >> 6; }
  const int K = 2048;
  bx *= 32; by *= 32;
  int tx = threadIdx.x & 31, ty = threadIdx.x >> 5;  // 32x8
#pragma unroll
  for (int r = 0; r < 32; r += 8)
    tile[ty + r][tx] = W[(size_t)(by + ty + r) * N + bx + tx];
  __syncthreads();
#pragma unroll
  for (int r = 0; r < 32; r += 8)
    Wt[(size_t)(bx + ty + r) * K + by + tx] = f2bf(tile[tx][ty + r]);
}

// ---------------- V slice of qkv -> vt[(b*NKV+kvh)*HD + d][t]  (bf16 transpose)
__global__ void transpose_v_kernel(const unsigned short* __restrict__ qkv,
                                   unsigned short* __restrict__ vt) {
  __shared__ unsigned short tile[32][33];
  int bh = blockIdx.z;                 // b*NKV + kvh
  int b = bh >> 2, kvh = bh & 3;
  int t0 = blockIdx.x * 32, d0 = blockIdx.y * 32;
  int tx = threadIdx.x & 31, ty = threadIdx.x >> 5;
#pragma unroll
  for (int r = 0; r < 32; r += 8)
    tile[ty + r][tx] = qkv[(size_t)(b * T_ + t0 + ty + r) * NQKV_ + 2560 + kvh * HD_ + d0 + tx];
  __syncthreads();
#pragma unroll
  for (int r = 0; r < 32; r += 8)
    vt[(size_t)(bh * HD_ + d0 + ty + r) * T_ + t0 + tx] = tile[tx][ty + r];
}

// ---------------- 8-phase bf16 GEMM (T3+T4+T5): C(MxN) = A(MxK)*Bt(NxK)^T.
// Tile BM x 256, BK=64 in 2 K-halves; 8 waves (4M x 2N), 512 thr. Fragments
// read via ASM ds_read_b128 (no compiler vmcnt drains); one lgkmcnt(0)+
// sched_barrier(0) per phase before MFMA (rule #18). vmcnt(6|4) at ph4/ph8
// only — never 0 in-loop. LDS XOR-swizzled via pre-swizzled global source.
template <int BM, typename OUT, bool ROPE>
__global__ __launch_bounds__(512, 1) void gemm8p(const unsigned short* __restrict__ A,
                                                 const unsigned short* __restrict__ Bt,
                                                 OUT* __restrict__ Cm,
                                                 const float2* __restrict__ rt,
                                                 int M, int N, int K) {
  constexpr int MR = BM / 64;  // A-frags per wave: 4 (BM=256) or 2 (BM=128)
  __shared__ __align__(16) unsigned short As[2][2][BM * 32];
  __shared__ __align__(16) unsigned short Bs[2][2][256 * 32];
  int tid = threadIdx.x, wid = tid >> 6, lane = tid & 63;
  int l15 = lane & 15, l4 = lane >> 4;
  int wr = wid >> 1, wc = wid & 1;  // 4M x 2N
  size_t arow0 = (size_t)blockIdx.y * BM;
  size_t brow0 = (size_t)blockIdx.x * 256;
  int tmax = K / 64 - 1;

  f32x4 acc[MR][8];
#pragma unroll
  for (int m = 0; m < MR; ++m)
#pragma unroll
    for (int n = 0; n < 8; ++n) acc[m][n] = (f32x4){0.f, 0.f, 0.f, 0.f};

  auto stageA = [&](int slot, int kh, int tile) {
    int k0 = tile * 64 + kh * 32;
    constexpr int NLD = (BM * 32 * 2) / (512 * 16);  // 2 (BM=256) or 1 (BM=128)
#pragma unroll
    for (int i = 0; i < NLD; ++i) {
      int c = i * 512 + wid * 64 + lane;
      int rg = c >> 2, cg = (c & 3) ^ (rg & 3);
      const unsigned short* g = A + (arow0 + rg) * K + k0 + cg * 8;
      GLOAD_LDS16(g, &As[slot][kh][c * 8]);
    }
  };
  auto stageB = [&](int slot, int kh, int tile) {
    int k0 = tile * 64 + kh * 32;
#pragma unroll
    for (int i = 0; i < 2; ++i) {
      int c = i * 512 + wid * 64 + lane;
      int rg = c >> 2, cg = (c & 3) ^ (rg & 3);
      const unsigned short* g = Bt + (brow0 + rg) * K + k0 + cg * 8;
      GLOAD_LDS16(g, &Bs[slot][kh][c * 8]);
    }
  };

  // prologue: tile0 {A00,B00,A01,B01}, tile1 {A10,B10,A11}; last 3 halves stay in flight
  stageA(0, 0, 0); stageB(0, 0, 0); stageA(0, 1, 0); stageB(0, 1, 0);
  stageA(1, 0, 1); stageB(1, 0, 1); stageA(1, 1, 1);
  if constexpr (BM == 256) asm volatile("s_waitcnt vmcnt(6)" ::: "memory");
  else                     asm volatile("s_waitcnt vmcnt(4)" ::: "memory");
  __builtin_amdgcn_s_barrier();

  int NT2 = K / 128;
  for (int it = 0; it < NT2; ++it) {
    int t2 = it * 2;
#pragma unroll
    for (int tt = 0; tt < 2; ++tt) {
      bf16x8 af[MR];
#pragma unroll
      for (int kh = 0; kh < 2; ++kh) {
#pragma unroll
        for (int nh = 0; nh < 2; ++nh) {
          int p = tt * 4 + kh * 2 + nh + 1;  // 1..8 (constant under unroll)
          // asm ds_reads: A frags once per (tt,kh); B frags every phase
          if (nh == 0) {
#pragma unroll
            for (int m = 0; m < MR; ++m) {
              int r = wr * (MR * 16) + m * 16 + l15;
              af[m] = ldsread128(&As[tt][kh][r * 32 + ((l4 ^ (r & 3)) * 8)]);
            }
          }
          bf16x8 bf[4];
#pragma unroll
          for (int j = 0; j < 4; ++j) {
            int r = wc * 128 + (nh * 4 + j) * 16 + l15;
            bf[j] = ldsread128(&Bs[tt][kh][r * 32 + ((l4 ^ (r & 3)) * 8)]);
          }
          // stage one half per phase (ledger-verified rotation, tail-clamped)
          if (p == 1) stageB(1, 1, t2 + 1);
          if (p == 2) stageA(0, 0, t2 + 2 <= tmax ? t2 + 2 : tmax);
          if (p == 3) stageB(0, 0, t2 + 2 <= tmax ? t2 + 2 : tmax);
          if (p == 4) stageA(0, 1, t2 + 2 <= tmax ? t2 + 2 : tmax);
          if (p == 5) stageB(0, 1, t2 + 2 <= tmax ? t2 + 2 : tmax);
          if (p == 6) stageA(1, 0, t2 + 3 <= tmax ? t2 + 3 : tmax);
          if (p == 7) stageB(1, 0, t2 + 3 <= tmax ? t2 + 3 : tmax);
          if (p == 8) stageA(1, 1, t2 + 3 <= tmax ? t2 + 3 : tmax);

          __builtin_amdgcn_s_barrier();
          asm volatile("s_waitcnt lgkmcnt(0)" ::: "memory");
          __builtin_amdgcn_sched_barrier(0);   // rule #18: fence asm ds_read vs MFMA
          __builtin_amdgcn_s_setprio(1);
#pragma unroll
          for (int m = 0; m < MR; ++m)
#pragma unroll
            for (int j = 0; j < 4; ++j)
              acc[m][nh * 4 + j] = __builtin_amdgcn_mfma_f32_16x16x32_bf16(
                  af[m], bf[j], acc[m][nh * 4 + j], 0, 0, 0);
          __builtin_amdgcn_s_setprio(0);
          if (p == 4 || p == 8) {
            if constexpr (BM == 256) asm volatile("s_waitcnt vmcnt(6)" ::: "memory");
            else                     asm volatile("s_waitcnt vmcnt(4)" ::: "memory");
          }
          __builtin_amdgcn_s_barrier();
        }
      }
    }
  }

  bool dorope = ROPE && (brow0 + wc * 128 < 2560);
#pragma unroll
  for (int m = 0; m < MR; ++m)
#pragma unroll
    for (int r = 0; r < 4; ++r) {
      size_t row = arow0 + wr * (MR * 16) + m * 16 + l4 * 4 + r;
      if (dorope) {
        int t = (int)(row & (T_ - 1));
#pragma unroll
        for (int n = 0; n < 4; ++n) {
          float2 cs = rt[t * 64 + n * 16 + l15];
          float a1 = acc[m][n][r], a2 = acc[m][n + 4][r];
          size_t col = brow0 + wc * 128 + n * 16 + l15;
          Cm[row * N + col]      = f2bf(a1 * cs.x - a2 * cs.y);
          Cm[row * N + col + 64] = f2bf(a2 * cs.x + a1 * cs.y);
        }
      } else {
#pragma unroll
        for (int n = 0; n < 8; ++n) {
          size_t col = brow0 + wc * 128 + n * 16 + l15;
          float v = acc[m][n][r];
          if constexpr (sizeof(OUT) == 4) Cm[row * N + col] = v;
          else                            Cm[row * N + col] = f2bf(v);
        }
      }
    }
}

// ---------------- flash attention (R8, proven 86.5us): QBLK=128 (4 waves x 32
// q-rows), KVBLK=64, GQA. 32x32 swapped QK^T, in-register softmax (exp2), P^T
// via xor-32 exchange. Prefetch-at-top, ONE barrier/iter. Balanced 1D grid,
// swizzled LDS, defer-max, diagonal-only masking, setprio.
__global__ __launch_bounds__(256, 2) void attn_kernel(const unsigned short* __restrict__ qkv,
                                                      const unsigned short* __restrict__ vt,
                                                      unsigned short* __restrict__ att) {
  constexpr int KB = 64;
  __shared__ __align__(16) unsigned short Kl[2][KB * 128];   // [kv][d] 32KB, swizzled
  __shared__ __align__(16) unsigned short Vl[2][128 * KB];   // [d][kv] 32KB, swizzled
  int tid = threadIdx.x, w = tid >> 6, lane = tid & 63;
  int l31 = lane & 31, hi = lane >> 5;
  int h4 = hi * 4;

  int id = blockIdx.x;
  int u = id & 255, half = id >> 8;
  int bh = u & 31;
  int qh = u >> 5;                       // 0..7
  int qi = half ? (15 - qh) : qh;        // 0..15
  int q0 = qi * 128;
  int b = bh >> 4, hd = bh & 15, kvh = hd >> 2;
  int qr0 = q0 + w * 32;   // this wave's first q row
  int ql = qr0 + l31;      // this lane's q row

  bf16x8 qf[8];
  {
    const unsigned short* qb = qkv + (size_t)(b * T_ + ql) * NQKV_ + hd * HD_ + hi * 8;
    const float scale = 0.08838834764831845f * 1.4426950408889634f;
#pragma unroll
    for (int df = 0; df < 8; ++df) {
      bf16x8 t = *reinterpret_cast<const bf16x8*>(qb + df * 16);
#pragma unroll
      for (int j = 0; j < 8; ++j) t[j] = (__bf16)((float)t[j] * scale);
      qf[df] = t;
    }
  }

  f32x16 o[4];
#pragma unroll
  for (int dt = 0; dt < 4; ++dt)
#pragma unroll
    for (int r = 0; r < 16; ++r) o[dt][r] = 0.f;
  float mr = -1e30f, lr = 0.f;

  auto stage = [&](int buf, int kv0) {
#pragma unroll
    for (int i = 0; i < 4; ++i) {  // K tile: chunk c ^= (row&7), row = c>>4
      int c = (i * 4 + w) * 64 + lane;
      int g = c ^ ((c >> 4) & 7);
      const unsigned short* src =
          qkv + (size_t)(b * T_ + kv0 + (g >> 4)) * NQKV_ + C_ + kvh * HD_ + (g & 15) * 8;
      GLOAD_LDS16(src, &Kl[buf][(i * 4 + w) * 512]);
    }
#pragma unroll
    for (int i = 0; i < 4; ++i) {  // V^T tile: chunk c ^= (row&7), row = c>>3
      int c = (i * 4 + w) * 64 + lane;
      int g = c ^ ((c >> 3) & 7);
      const unsigned short* src =
          vt + (size_t)((b * NKV_ + kvh) * HD_ + (g >> 3)) * T_ + kv0 + (g & 7) * 8;
      GLOAD_LDS16(src, &Vl[buf][(i * 4 + w) * 512]);
    }
  };

  int nt = q0 / KB + 2;
  stage(0, 0);
  __syncthreads();
  int cur = 0;
  for (int kt = 0; kt < nt; ++kt) {
    int kv0 = kt * KB;
    if (kt + 1 < nt) stage(cur ^ 1, kv0 + KB);

    if (kv0 <= qr0 + 31) {
      f32x16 s[2];
#pragma unroll
      for (int r = 0; r < 16; ++r) { s[0][r] = 0.f; s[1][r] = 0.f; }
      const unsigned short* Kb = &Kl[cur][0];
      __builtin_amdgcn_s_setprio(1);
#pragma unroll
      for (int t2 = 0; t2 < 2; ++t2)
#pragma unroll
        for (int df = 0; df < 8; ++df) {
          bf16x8 kf = *reinterpret_cast<const bf16x8*>(
              Kb + (((t2 * 32 + l31) * 128 + df * 16 + hi * 8) ^ ((l31 & 7) << 3)));
          s[t2] = __builtin_amdgcn_mfma_f32_32x32x16_bf16(kf, qf[df], s[t2], 0, 0, 0);
        }
      __builtin_amdgcn_s_setprio(0);

      float rm = -1e30f;
      if ((kv0 + KB - 1) > qr0) {
#pragma unroll
        for (int t2 = 0; t2 < 2; ++t2)
#pragma unroll
          for (int r = 0; r < 16; ++r) {
            float sv = s[t2][r];
            int kcol = kv0 + t2 * 32 + (r & 3) + 8 * (r >> 2) + h4;
            if (kcol > ql) sv = -1e30f;
            s[t2][r] = sv;
            rm = fmaxf(rm, sv);
          }
      } else {
#pragma unroll
        for (int t2 = 0; t2 < 2; ++t2)
#pragma unroll
          for (int r = 0; r < 16; ++r) rm = fmaxf(rm, s[t2][r]);
      }
      rm = fmaxf(rm, __shfl_xor(rm, 32));

      if (!__all(rm <= mr + 11.0f)) {
        float mnew = fmaxf(mr, rm);
        float alpha = exp2f(mr - mnew);
        mr = mnew;
        lr *= alpha;
#pragma unroll
        for (int dt = 0; dt < 4; ++dt)
#pragma unroll
          for (int r = 0; r < 16; ++r) o[dt][r] *= alpha;
      }

      float ps = 0.f;
#pragma unroll
      for (int t2 = 0; t2 < 2; ++t2)
#pragma unroll
        for (int r = 0; r < 16; ++r) {
          float p = exp2f(s[t2][r] - mr);
          s[t2][r] = p;
          ps += p;
        }
      lr += ps;

      unsigned pk[2][8];
#pragma unroll
      for (int t2 = 0; t2 < 2; ++t2)
#pragma unroll
        for (int i = 0; i < 8; ++i) {
          union { unsigned u32; __bf16 hh[2]; } pr;
          pr.hh[0] = (__bf16)s[t2][2 * i];
          pr.hh[1] = (__bf16)s[t2][2 * i + 1];
          pk[t2][i] = pr.u32;
        }

      bf16x8 pb[4];
#pragma unroll
      for (int f = 0; f < 4; ++f) {
        int t2 = f >> 1, bq = (f & 1) * 4;
        union { bf16x8 v; unsigned d[4]; } fr;
#pragma unroll
        for (int p = 0; p < 2; ++p) {
          unsigned uu = pk[t2][bq + p];
          unsigned ww = pk[t2][bq + 2 + p];
          unsigned us = (unsigned)__shfl_xor((int)uu, 32);
          unsigned ws = (unsigned)__shfl_xor((int)ww, 32);
          fr.d[p]     = hi ? ws : uu;
          fr.d[2 + p] = hi ? ww : us;
        }
        pb[f] = fr.v;
      }

      const unsigned short* Vb = &Vl[cur][0];
      __builtin_amdgcn_s_setprio(1);
#pragma unroll
      for (int dt = 0; dt < 4; ++dt)
#pragma unroll
        for (int kf = 0; kf < 4; ++kf) {
          bf16x8 vf = *reinterpret_cast<const bf16x8*>(
              Vb + (((dt * 32 + l31) * KB + kf * 16 + hi * 8) ^ ((l31 & 7) << 3)));
          o[dt] = __builtin_amdgcn_mfma_f32_32x32x16_bf16(vf, pb[kf], o[dt], 0, 0, 0);
        }
      __builtin_amdgcn_s_setprio(0);
    }

    __syncthreads();
    cur ^= 1;
  }

  float ls = lr + __shfl_xor(lr, 32);
  float inv = 1.f / ls;
  unsigned short* ob = att + (size_t)(b * T_ + ql) * C_ + hd * HD_;
#pragma unroll
  for (int dt = 0; dt < 4; ++dt)
#pragma unroll
    for (int r = 0; r < 16; ++r) {
      int d = dt * 32 + (r & 3) + 8 * (r >> 2) + h4;
      ob[d] = f2bf(o[dt][r] * inv);
    }
}

extern "C" void kernel_launch(void* const* d_in, const int* in_sizes, int n_in,
                              void* d_out, int out_size, void* d_ws, size_t ws_size,
                              hipStream_t stream) {
  const float* x  = (const float*)d_in[0];
  const float* Wq = (const float*)d_in[1];
  const float* Wk = (const float*)d_in[2];
  const float* Wv = (const float*)d_in[3];
  const float* Wp = (const float*)d_in[4];
  float* out = (float*)d_out;
  char* ws = (char*)d_ws;

  // workspace layout (bytes); total 68,157,440
  unsigned short* xb  = (unsigned short*)(ws);              // 16MB  x bf16 (att aliases)
  unsigned short* wt  = (unsigned short*)(ws + 16777216);   // 20MB  Wq^T|Wk^T|Wv^T|Wp^T
  unsigned short* qkv = (unsigned short*)(ws + 37748736);   // 24MB  q(rope)|k(rope)|v
  float2*         rt  = (float2*)(ws + 62914560);           // 1MB   cos/sin
  unsigned short* vt  = (unsigned short*)(ws + 63963136);   // 4MB   V d-major [bh*HD+d][t]
  unsigned short* att = xb;                                 // alias: xb dead after GEMM1

  rope_table_kernel<<<T_, 64, 0, stream>>>(rt);
  convx_kernel<<<(M_ * C_ / 4 + 255) / 256, 256, 0, stream>>>(x, xb, M_ * C_ / 4);
  transpose_conv4_kernel<<<dim3(10240), 256, 0, stream>>>(Wq, Wk, Wv, Wp, wt);

  gemm8p<256, unsigned short, true><<<dim3(NQKV_ / 256, M_ / 256), 512, 0, stream>>>(
      xb, wt, qkv, rt, M_, NQKV_, C_);
  transpose_v_kernel<<<dim3(T_ / 32, HD_ / 32, B_ * NKV_), 256, 0, stream>>>(qkv, vt);
  attn_kernel<<<dim3(512), 256, 0, stream>>>(qkv, vt, att);
  gemm8p<128, float, false><<<dim3(C_ / 256, M_ / 128), 512, 0, stream>>>(
      att, wt + (size_t)3072 * 2048, out, nullptr, M_, C_, C_);
}

// Round 15
// 214.466 us; speedup vs baseline: 1.2710x; 1.0058x over previous
//
#include <hip/hip_runtime.h>

#define B_ 2
#define T_ 2048
#define C_ 2048
#define NH_ 16
#define NKV_ 4
#define HD_ 128
#define M_ 4096          // B*T
#define NQKV_ 3072

typedef __bf16 bf16x8 __attribute__((ext_vector_type(8)));
typedef float f32x4 __attribute__((ext_vector_type(4)));
typedef float f32x16 __attribute__((ext_vector_type(16)));

__device__ __forceinline__ unsigned short f2bf(float f) {
  union { float f; unsigned u; } c{f};
  unsigned u = c.u + 0x7FFFu + ((c.u >> 16) & 1u);
  return (unsigned short)(u >> 16);
}
__device__ __forceinline__ float bf2f(unsigned short h) {
  union { unsigned u; float f; } c{(unsigned)h << 16};
  return c.f;
}

#define GLOAD_LDS16(g, l)                                        \
  __builtin_amdgcn_global_load_lds(                              \
      (const __attribute__((address_space(1))) void*)(g),        \
      (__attribute__((address_space(3))) void*)(l), 16, 0, 0)

// asm ds_read_b128: opaque to alias analysis -> no compiler-inserted vmcnt
// drains against outstanding global_load_lds (rule #18: fence with
// lgkmcnt(0) + sched_barrier(0) before consuming).
__device__ __forceinline__ bf16x8 ldsread128(const unsigned short* p) {
  uint4 d;
  asm volatile("ds_read_b128 %0, %1"
               : "=v"(d)
               : "v"((const __attribute__((address_space(3))) void*)p));
  union { uint4 u; bf16x8 v; } c;
  c.u = d;
  return c.v;
}

// ---------------- fused prep: weight transposes + x->bf16 + rope table
__global__ void prep_kernel(const float* __restrict__ x, const float* __restrict__ Wq,
                            const float* __restrict__ Wk, const float* __restrict__ Wv,
                            const float* __restrict__ Wp, unsigned short* __restrict__ xb,
                            unsigned short* __restrict__ wt, float2* __restrict__ rt) {
  int id = blockIdx.x;
  if (id < 10240) {  // weight transpose-convert
    __shared__ float tile[32][33];
    const float* W;
    unsigned short* Wt;
    int N, bx, by;
    if (id < 4096)      { W = Wq; Wt = wt;                       N = 2048; int u = id;        bx = u & 63; by = u >> 6; }
    else if (id < 5120) { W = Wk; Wt = wt + (size_t)2048 * 2048; N = 512;  int u = id - 4096; bx = u & 15; by = u >> 4; }
    else if (id < 6144) { W = Wv; Wt = wt + (size_t)2560 * 2048; N = 512;  int u = id - 5120; bx = u & 15; by = u >> 4; }
    else                { W = Wp; Wt = wt + (size_t)3072 * 2048; N = 2048; int u = id - 6144; bx = u & 63; by = u >> 6; }
    const int K = 2048;
    bx *= 32; by *= 32;
    int tx = threadIdx.x & 31, ty = threadIdx.x >> 5;
#pragma unroll
    for (int r = 0; r < 32; r += 8)
      tile[ty + r][tx] = W[(size_t)(by + ty + r) * N + bx + tx];
    __syncthreads();
#pragma unroll
    for (int r = 0; r < 32; r += 8)
      Wt[(size_t)(bx + ty + r) * K + by + tx] = f2bf(tile[tx][ty + r]);
  } else if (id < 18432) {  // x f32 -> bf16, float4 chunks
    int i = (id - 10240) * 256 + threadIdx.x;  // < 2097152 exactly
    float4 v = reinterpret_cast<const float4*>(x)[i];
    union { ushort4 u; unsigned short s[4]; } o;
    o.s[0] = f2bf(v.x); o.s[1] = f2bf(v.y); o.s[2] = f2bf(v.z); o.s[3] = f2bf(v.w);
    reinterpret_cast<ushort4*>(xb)[i] = o.u;
  } else {  // rope table
    int g = (id - 18432) * 256 + threadIdx.x;  // < 131072 exactly
    int t = g >> 6, i = g & 63;
    float inv = powf(10000.f, -(float)(2 * i) / 128.f);
    float s, c;
    sincosf((float)t * inv, &s, &c);
    rt[t * 64 + i] = make_float2(c, s);
  }
}

// ---------------- V slice of qkv -> vt[(b*NKV+kvh)*HD + d][t]  (bf16 transpose)
__global__ void transpose_v_kernel(const unsigned short* __restrict__ qkv,
                                   unsigned short* __restrict__ vt) {
  __shared__ unsigned short tile[32][33];
  int bh = blockIdx.z;                 // b*NKV + kvh
  int b = bh >> 2, kvh = bh & 3;
  int t0 = blockIdx.x * 32, d0 = blockIdx.y * 32;
  int tx = threadIdx.x & 31, ty = threadIdx.x >> 5;
#pragma unroll
  for (int r = 0; r < 32; r += 8)
    tile[ty + r][tx] = qkv[(size_t)(b * T_ + t0 + ty + r) * NQKV_ + 2560 + kvh * HD_ + d0 + tx];
  __syncthreads();
#pragma unroll
  for (int r = 0; r < 32; r += 8)
    vt[(size_t)(bh * HD_ + d0 + ty + r) * T_ + t0 + tx] = tile[tx][ty + r];
}

// ---------------- 8-phase bf16 GEMM (T3+T4+T5), asm ds_read (R14, proven)
template <int BM, typename OUT, bool ROPE>
__global__ __launch_bounds__(512, 1) void gemm8p(const unsigned short* __restrict__ A,
                                                 const unsigned short* __restrict__ Bt,
                                                 OUT* __restrict__ Cm,
                                                 const float2* __restrict__ rt,
                                                 int M, int N, int K) {
  constexpr int MR = BM / 64;
  __shared__ __align__(16) unsigned short As[2][2][BM * 32];
  __shared__ __align__(16) unsigned short Bs[2][2][256 * 32];
  int tid = threadIdx.x, wid = tid >> 6, lane = tid & 63;
  int l15 = lane & 15, l4 = lane >> 4;
  int wr = wid >> 1, wc = wid & 1;
  size_t arow0 = (size_t)blockIdx.y * BM;
  size_t brow0 = (size_t)blockIdx.x * 256;
  int tmax = K / 64 - 1;

  f32x4 acc[MR][8];
#pragma unroll
  for (int m = 0; m < MR; ++m)
#pragma unroll
    for (int n = 0; n < 8; ++n) acc[m][n] = (f32x4){0.f, 0.f, 0.f, 0.f};

  auto stageA = [&](int slot, int kh, int tile) {
    int k0 = tile * 64 + kh * 32;
    constexpr int NLD = (BM * 32 * 2) / (512 * 16);
#pragma unroll
    for (int i = 0; i < NLD; ++i) {
      int c = i * 512 + wid * 64 + lane;
      int rg = c >> 2, cg = (c & 3) ^ (rg & 3);
      const unsigned short* g = A + (arow0 + rg) * K + k0 + cg * 8;
      GLOAD_LDS16(g, &As[slot][kh][c * 8]);
    }
  };
  auto stageB = [&](int slot, int kh, int tile) {
    int k0 = tile * 64 + kh * 32;
#pragma unroll
    for (int i = 0; i < 2; ++i) {
      int c = i * 512 + wid * 64 + lane;
      int rg = c >> 2, cg = (c & 3) ^ (rg & 3);
      const unsigned short* g = Bt + (brow0 + rg) * K + k0 + cg * 8;
      GLOAD_LDS16(g, &Bs[slot][kh][c * 8]);
    }
  };

  stageA(0, 0, 0); stageB(0, 0, 0); stageA(0, 1, 0); stageB(0, 1, 0);
  stageA(1, 0, 1); stageB(1, 0, 1); stageA(1, 1, 1);
  if constexpr (BM == 256) asm volatile("s_waitcnt vmcnt(6)" ::: "memory");
  else                     asm volatile("s_waitcnt vmcnt(4)" ::: "memory");
  __builtin_amdgcn_s_barrier();

  int NT2 = K / 128;
  for (int it = 0; it < NT2; ++it) {
    int t2 = it * 2;
#pragma unroll
    for (int tt = 0; tt < 2; ++tt) {
      bf16x8 af[MR];
#pragma unroll
      for (int kh = 0; kh < 2; ++kh) {
#pragma unroll
        for (int nh = 0; nh < 2; ++nh) {
          int p = tt * 4 + kh * 2 + nh + 1;
          if (nh == 0) {
#pragma unroll
            for (int m = 0; m < MR; ++m) {
              int r = wr * (MR * 16) + m * 16 + l15;
              af[m] = ldsread128(&As[tt][kh][r * 32 + ((l4 ^ (r & 3)) * 8)]);
            }
          }
          bf16x8 bf[4];
#pragma unroll
          for (int j = 0; j < 4; ++j) {
            int r = wc * 128 + (nh * 4 + j) * 16 + l15;
            bf[j] = ldsread128(&Bs[tt][kh][r * 32 + ((l4 ^ (r & 3)) * 8)]);
          }
          if (p == 1) stageB(1, 1, t2 + 1);
          if (p == 2) stageA(0, 0, t2 + 2 <= tmax ? t2 + 2 : tmax);
          if (p == 3) stageB(0, 0, t2 + 2 <= tmax ? t2 + 2 : tmax);
          if (p == 4) stageA(0, 1, t2 + 2 <= tmax ? t2 + 2 : tmax);
          if (p == 5) stageB(0, 1, t2 + 2 <= tmax ? t2 + 2 : tmax);
          if (p == 6) stageA(1, 0, t2 + 3 <= tmax ? t2 + 3 : tmax);
          if (p == 7) stageB(1, 0, t2 + 3 <= tmax ? t2 + 3 : tmax);
          if (p == 8) stageA(1, 1, t2 + 3 <= tmax ? t2 + 3 : tmax);

          __builtin_amdgcn_s_barrier();
          asm volatile("s_waitcnt lgkmcnt(0)" ::: "memory");
          __builtin_amdgcn_sched_barrier(0);
          __builtin_amdgcn_s_setprio(1);
#pragma unroll
          for (int m = 0; m < MR; ++m)
#pragma unroll
            for (int j = 0; j < 4; ++j)
              acc[m][nh * 4 + j] = __builtin_amdgcn_mfma_f32_16x16x32_bf16(
                  af[m], bf[j], acc[m][nh * 4 + j], 0, 0, 0);
          __builtin_amdgcn_s_setprio(0);
          if (p == 4 || p == 8) {
            if constexpr (BM == 256) asm volatile("s_waitcnt vmcnt(6)" ::: "memory");
            else                     asm volatile("s_waitcnt vmcnt(4)" ::: "memory");
          }
          __builtin_amdgcn_s_barrier();
        }
      }
    }
  }

  bool dorope = ROPE && (brow0 + wc * 128 < 2560);
#pragma unroll
  for (int m = 0; m < MR; ++m)
#pragma unroll
    for (int r = 0; r < 4; ++r) {
      size_t row = arow0 + wr * (MR * 16) + m * 16 + l4 * 4 + r;
      if (dorope) {
        int t = (int)(row & (T_ - 1));
#pragma unroll
        for (int n = 0; n < 4; ++n) {
          float2 cs = rt[t * 64 + n * 16 + l15];
          float a1 = acc[m][n][r], a2 = acc[m][n + 4][r];
          size_t col = brow0 + wc * 128 + n * 16 + l15;
          Cm[row * N + col]      = f2bf(a1 * cs.x - a2 * cs.y);
          Cm[row * N + col + 64] = f2bf(a2 * cs.x + a1 * cs.y);
        }
      } else {
#pragma unroll
        for (int n = 0; n < 8; ++n) {
          size_t col = brow0 + wc * 128 + n * 16 + l15;
          float v = acc[m][n][r];
          if constexpr (sizeof(OUT) == 4) Cm[row * N + col] = v;
          else                            Cm[row * N + col] = f2bf(v);
        }
      }
    }
}

// ---------------- flash attention (R8 inner loop, KV-split scheduling):
// 704 blocks, LPT order: qi 9,8 unsplit (longest) -> qi 15..10 split in two
// KV-halves (partial m/l/O output) -> qi 7..0 unsplit. Combine pass merges
// split halves. Inner loop byte-identical to the proven R8 structure.
__global__ __launch_bounds__(256, 2) void attn_kernel(const unsigned short* __restrict__ qkv,
                                                      const unsigned short* __restrict__ vt,
                                                      unsigned short* __restrict__ att,
                                                      unsigned short* __restrict__ pO,
                                                      float2* __restrict__ ml) {
  constexpr int KB = 64;
  __shared__ __align__(16) unsigned short Kl[2][KB * 128];
  __shared__ __align__(16) unsigned short Vl[2][128 * KB];
  int tid = threadIdx.x, w = tid >> 6, lane = tid & 63;
  int l31 = lane & 31, hi = lane >> 5;
  int h4 = hi * 4;

  // LPT decode
  int id = blockIdx.x;
  int qi, bh, kt0, kt1, slot = -1;
  if (id < 64) {                       // unsplit qi 9,8 (longest items first)
    qi = 9 - (id >> 5); bh = id & 31; kt0 = 0; kt1 = 2 * qi + 2;
  } else if (id < 448) {               // split qi 15..10, two KV halves
    int s = id - 64;                   // 0..383 = partial slot
    int pairidx = s >> 1, hihalf = s & 1;
    qi = 15 - (pairidx >> 5); bh = pairidx & 31;
    int nt = 2 * qi + 2, h = nt >> 1;
    kt0 = hihalf ? h : 0; kt1 = hihalf ? nt : h;
    slot = s;
  } else {                             // unsplit qi 7..0
    int u = id - 448;
    qi = 7 - (u >> 5); bh = u & 31; kt0 = 0; kt1 = 2 * qi + 2;
  }
  int q0 = qi * 128;
  int b = bh >> 4, hd = bh & 15, kvh = hd >> 2;
  int qr0 = q0 + w * 32;
  int ql = qr0 + l31;

  bf16x8 qf[8];
  {
    const unsigned short* qb = qkv + (size_t)(b * T_ + ql) * NQKV_ + hd * HD_ + hi * 8;
    const float scale = 0.08838834764831845f * 1.4426950408889634f;
#pragma unroll
    for (int df = 0; df < 8; ++df) {
      bf16x8 t = *reinterpret_cast<const bf16x8*>(qb + df * 16);
#pragma unroll
      for (int j = 0; j < 8; ++j) t[j] = (__bf16)((float)t[j] * scale);
      qf[df] = t;
    }
  }

  f32x16 o[4];
#pragma unroll
  for (int dt = 0; dt < 4; ++dt)
#pragma unroll
    for (int r = 0; r < 16; ++r) o[dt][r] = 0.f;
  float mr = -1e30f, lr = 0.f;

  auto stage = [&](int buf, int kv0) {
#pragma unroll
    for (int i = 0; i < 4; ++i) {
      int c = (i * 4 + w) * 64 + lane;
      int g = c ^ ((c >> 4) & 7);
      const unsigned short* src =
          qkv + (size_t)(b * T_ + kv0 + (g >> 4)) * NQKV_ + C_ + kvh * HD_ + (g & 15) * 8;
      GLOAD_LDS16(src, &Kl[buf][(i * 4 + w) * 512]);
    }
#pragma unroll
    for (int i = 0; i < 4; ++i) {
      int c = (i * 4 + w) * 64 + lane;
      int g = c ^ ((c >> 3) & 7);
      const unsigned short* src =
          vt + (size_t)((b * NKV_ + kvh) * HD_ + (g >> 3)) * T_ + kv0 + (g & 7) * 8;
      GLOAD_LDS16(src, &Vl[buf][(i * 4 + w) * 512]);
    }
  };

  stage(0, kt0 * KB);
  __syncthreads();
  int cur = 0;
  for (int kt = kt0; kt < kt1; ++kt) {
    int kv0 = kt * KB;
    if (kt + 1 < kt1) stage(cur ^ 1, kv0 + KB);

    if (kv0 <= qr0 + 31) {
      f32x16 s[2];
#pragma unroll
      for (int r = 0; r < 16; ++r) { s[0][r] = 0.f; s[1][r] = 0.f; }
      const unsigned short* Kb = &Kl[cur][0];
      __builtin_amdgcn_s_setprio(1);
#pragma unroll
      for (int t2 = 0; t2 < 2; ++t2)
#pragma unroll
        for (int df = 0; df < 8; ++df) {
          bf16x8 kf = *reinterpret_cast<const bf16x8*>(
              Kb + (((t2 * 32 + l31) * 128 + df * 16 + hi * 8) ^ ((l31 & 7) << 3)));
          s[t2] = __builtin_amdgcn_mfma_f32_32x32x16_bf16(kf, qf[df], s[t2], 0, 0, 0);
        }
      __builtin_amdgcn_s_setprio(0);

      float rm = -1e30f;
      if ((kv0 + KB - 1) > qr0) {
#pragma unroll
        for (int t2 = 0; t2 < 2; ++t2)
#pragma unroll
          for (int r = 0; r < 16; ++r) {
            float sv = s[t2][r];
            int kcol = kv0 + t2 * 32 + (r & 3) + 8 * (r >> 2) + h4;
            if (kcol > ql) sv = -1e30f;
            s[t2][r] = sv;
            rm = fmaxf(rm, sv);
          }
      } else {
#pragma unroll
        for (int t2 = 0; t2 < 2; ++t2)
#pragma unroll
          for (int r = 0; r < 16; ++r) rm = fmaxf(rm, s[t2][r]);
      }
      rm = fmaxf(rm, __shfl_xor(rm, 32));

      if (!__all(rm <= mr + 11.0f)) {
        float mnew = fmaxf(mr, rm);
        float alpha = exp2f(mr - mnew);
        mr = mnew;
        lr *= alpha;
#pragma unroll
        for (int dt = 0; dt < 4; ++dt)
#pragma unroll
          for (int r = 0; r < 16; ++r) o[dt][r] *= alpha;
      }

      float ps = 0.f;
#pragma unroll
      for (int t2 = 0; t2 < 2; ++t2)
#pragma unroll
        for (int r = 0; r < 16; ++r) {
          float p = exp2f(s[t2][r] - mr);
          s[t2][r] = p;
          ps += p;
        }
      lr += ps;

      unsigned pk[2][8];
#pragma unroll
      for (int t2 = 0; t2 < 2; ++t2)
#pragma unroll
        for (int i = 0; i < 8; ++i) {
          union { unsigned u32; __bf16 hh[2]; } pr;
          pr.hh[0] = (__bf16)s[t2][2 * i];
          pr.hh[1] = (__bf16)s[t2][2 * i + 1];
          pk[t2][i] = pr.u32;
        }

      bf16x8 pb[4];
#pragma unroll
      for (int f = 0; f < 4; ++f) {
        int t2 = f >> 1, bq = (f & 1) * 4;
        union { bf16x8 v; unsigned d[4]; } fr;
#pragma unroll
        for (int p = 0; p < 2; ++p) {
          unsigned uu = pk[t2][bq + p];
          unsigned ww = pk[t2][bq + 2 + p];
          unsigned us = (unsigned)__shfl_xor((int)uu, 32);
          unsigned ws = (unsigned)__shfl_xor((int)ww, 32);
          fr.d[p]     = hi ? ws : uu;
          fr.d[2 + p] = hi ? ww : us;
        }
        pb[f] = fr.v;
      }

      const unsigned short* Vb = &Vl[cur][0];
      __builtin_amdgcn_s_setprio(1);
#pragma unroll
      for (int dt = 0; dt < 4; ++dt)
#pragma unroll
        for (int kf = 0; kf < 4; ++kf) {
          bf16x8 vf = *reinterpret_cast<const bf16x8*>(
              Vb + (((dt * 32 + l31) * KB + kf * 16 + hi * 8) ^ ((l31 & 7) << 3)));
          o[dt] = __builtin_amdgcn_mfma_f32_32x32x16_bf16(vf, pb[kf], o[dt], 0, 0, 0);
        }
      __builtin_amdgcn_s_setprio(0);
    }

    __syncthreads();
    cur ^= 1;
  }

  float ls = lr + __shfl_xor(lr, 32);
  if (slot < 0) {
    float inv = 1.f / ls;
    unsigned short* ob = att + (size_t)(b * T_ + ql) * C_ + hd * HD_;
#pragma unroll
    for (int dt = 0; dt < 4; ++dt)
#pragma unroll
      for (int r = 0; r < 16; ++r) {
        int d = dt * 32 + (r & 3) + 8 * (r >> 2) + h4;
        ob[d] = f2bf(o[dt][r] * inv);
      }
  } else {
    // partial: unnormalized O (bf16) + (m, l) per q-row
    int lrow = w * 32 + l31;
    unsigned short* po = pO + (size_t)slot * 16384 + lrow * 128;
#pragma unroll
    for (int dt = 0; dt < 4; ++dt)
#pragma unroll
      for (int r = 0; r < 16; ++r) {
        int d = dt * 32 + (r & 3) + 8 * (r >> 2) + h4;
        po[d] = f2bf(o[dt][r]);
      }
    if (hi == 0) ml[slot * 128 + lrow] = make_float2(mr, ls);
  }
}

// ---------------- merge KV-split halves: O = (w0*O0 + w1*O1) / (w0*l0 + w1*l1)
__global__ void combine_kernel(const unsigned short* __restrict__ pO,
                               const float2* __restrict__ ml,
                               unsigned short* __restrict__ att) {
  int pairidx = blockIdx.x;            // 0..191
  int qi = 15 - (pairidx >> 5), bh = pairidx & 31;
  int b = bh >> 4, hd = bh & 15;
  int q0 = qi * 128;
  int s0 = pairidx * 2, s1 = s0 + 1;
  int tid = threadIdx.x;               // 256: 2 threads per row, 64 d each
  int row = tid >> 1, dh = (tid & 1) * 64;
  float2 ml0 = ml[s0 * 128 + row], ml1 = ml[s1 * 128 + row];
  float m = fmaxf(ml0.x, ml1.x);
  float w0 = exp2f(ml0.x - m), w1 = exp2f(ml1.x - m);
  float inv = 1.f / (w0 * ml0.y + w1 * ml1.y);
  const unsigned short* p0 = pO + (size_t)s0 * 16384 + row * 128 + dh;
  const unsigned short* p1 = pO + (size_t)s1 * 16384 + row * 128 + dh;
  unsigned short* ob = att + (size_t)(b * T_ + q0 + row) * C_ + hd * HD_ + dh;
#pragma unroll
  for (int j = 0; j < 64; j += 4) {
    ushort4 a = *reinterpret_cast<const ushort4*>(p0 + j);
    ushort4 c = *reinterpret_cast<const ushort4*>(p1 + j);
    ushort4 r;
    r.x = f2bf((w0 * bf2f(a.x) + w1 * bf2f(c.x)) * inv);
    r.y = f2bf((w0 * bf2f(a.y) + w1 * bf2f(c.y)) * inv);
    r.z = f2bf((w0 * bf2f(a.z) + w1 * bf2f(c.z)) * inv);
    r.w = f2bf((w0 * bf2f(a.w) + w1 * bf2f(c.w)) * inv);
    *reinterpret_cast<ushort4*>(ob + j) = r;
  }
}

extern "C" void kernel_launch(void* const* d_in, const int* in_sizes, int n_in,
                              void* d_out, int out_size, void* d_ws, size_t ws_size,
                              hipStream_t stream) {
  const float* x  = (const float*)d_in[0];
  const float* Wq = (const float*)d_in[1];
  const float* Wk = (const float*)d_in[2];
  const float* Wv = (const float*)d_in[3];
  const float* Wp = (const float*)d_in[4];
  float* out = (float*)d_out;
  char* ws = (char*)d_ws;

  // workspace layout (bytes); total 68,157,440
  unsigned short* xb  = (unsigned short*)(ws);              // 16MB  x bf16 (att aliases)
  unsigned short* wt  = (unsigned short*)(ws + 16777216);   // 20MB  Wq^T|Wk^T|Wv^T|Wp^T
  unsigned short* qkv = (unsigned short*)(ws + 37748736);   // 24MB  q(rope)|k(rope)|v
  float2*         rt  = (float2*)(ws + 62914560);           // 1MB   cos/sin (dead after GEMM1)
  unsigned short* vt  = (unsigned short*)(ws + 63963136);   // 4MB   V d-major [bh*HD+d][t]
  unsigned short* att = xb;                                 // alias: xb dead after GEMM1
  unsigned short* pO  = wt;                                 // alias: Wq/k/v^T dead after GEMM1 (12.58MB)
  float2*         ml  = rt;                                 // alias: rt dead after GEMM1 (393KB)

  prep_kernel<<<dim3(18944), 256, 0, stream>>>(x, Wq, Wk, Wv, Wp, xb, wt, rt);

  gemm8p<256, unsigned short, true><<<dim3(NQKV_ / 256, M_ / 256), 512, 0, stream>>>(
      xb, wt, qkv, rt, M_, NQKV_, C_);
  transpose_v_kernel<<<dim3(T_ / 32, HD_ / 32, B_ * NKV_), 256, 0, stream>>>(qkv, vt);
  attn_kernel<<<dim3(704), 256, 0, stream>>>(qkv, vt, att, pO, ml);
  combine_kernel<<<dim3(192), 256, 0, stream>>>(pO, ml, att);
  gemm8p<128, float, false><<<dim3(C_ / 256, M_ / 128), 512, 0, stream>>>(
      att, wt + (size_t)3072 * 2048, out, nullptr, M_, C_, C_);
}